// Round 1
// baseline (16548.720 us; speedup 1.0000x reference)
//
#include <hip/hip_runtime.h>
#include <cmath>

// D = 128 feature dim throughout.
static constexpr int FD = 128;

// ---------------- count kernel: cnt[idx[e]] += 1 ----------------
__global__ void k_count(const int* __restrict__ idx, float* __restrict__ cnt, int E) {
    int e = blockIdx.x * blockDim.x + threadIdx.x;
    if (e < E) unsafeAtomicAdd(&cnt[idx[e]], 1.0f);
}

// ------- generic edge scatter: out[sidx[e]] += feat[gidx[e]] * (w?w[e]:1) -------
// 32 threads per edge, each handles 4 consecutive floats (float4 gather).
__global__ void k_scatter(const float* __restrict__ feat, const float* __restrict__ w,
                          const int* __restrict__ gidx, const int* __restrict__ sidx,
                          float* __restrict__ out, int E) {
    int t = blockIdx.x * blockDim.x + threadIdx.x;
    int e = t >> 5;
    if (e >= E) return;
    int c4 = (t & 31) * 4;
    const float4 v = *reinterpret_cast<const float4*>(&feat[(long long)gidx[e] * FD + c4]);
    float ww = w ? w[e] : 1.0f;
    float* o = &out[(long long)sidx[e] * FD + c4];
    unsafeAtomicAdd(o + 0, v.x * ww);
    unsafeAtomicAdd(o + 1, v.y * ww);
    unsafeAtomicAdd(o + 2, v.z * ww);
    unsafeAtomicAdd(o + 3, v.w * ww);
}

// ------- combine: sum[n,:] = (sum[n,:]/max(cnt[n],1) + xm[n,:]) * 0.5 (in place) -------
__global__ void k_combine(float* __restrict__ sum, const float* __restrict__ cnt,
                          const float* __restrict__ xm, int N) {
    int t = blockIdx.x * blockDim.x + threadIdx.x;
    if (t >= N * 32) return;
    int n = t >> 5;
    int c4 = (t & 31) * 4;
    float inv = 1.0f / fmaxf(cnt[n], 1.0f);
    long long base = (long long)n * FD + c4;
    float4 s = *reinterpret_cast<float4*>(&sum[base]);
    float4 x = *reinterpret_cast<const float4*>(&xm[base]);
    s.x = (s.x * inv + x.x) * 0.5f;
    s.y = (s.y * inv + x.y) * 0.5f;
    s.z = (s.z * inv + x.z) * 0.5f;
    s.w = (s.w * inv + x.w) * 0.5f;
    *reinterpret_cast<float4*>(&sum[base]) = s;
}

// ------- lin_relu in-place: xio[n,:] = relu((xio[n,:]/max(cnt[n],1)) @ W^T + b) -------
// Block = 256 threads handles 8 rows. x rows staged in LDS (so in-place write is safe),
// W staged in LDS in two 128x64 half-tiles (pad 65 -> conflict-free: bank=(o+i)%32).
__global__ __launch_bounds__(256) void k_linrelu(float* __restrict__ xio,
                                                 const float* __restrict__ cnt,
                                                 const float* __restrict__ W,
                                                 const float* __restrict__ b, int N) {
    __shared__ float xs[8][129];
    __shared__ float Wl[128][65];
    int t = threadIdx.x;
    int row0 = blockIdx.x * 8;
    // stage x rows (with scatter-mean divide)
    {
        int r = t >> 5, c4 = (t & 31) * 4;
        int row = row0 + r;
        float4 v = make_float4(0.f, 0.f, 0.f, 0.f);
        float inv = 1.0f;
        if (row < N) {
            inv = 1.0f / fmaxf(cnt ? cnt[row] : 1.0f, 1.0f);
            v = *reinterpret_cast<const float4*>(&xio[(long long)row * FD + c4]);
        }
        xs[r][c4 + 0] = v.x * inv;
        xs[r][c4 + 1] = v.y * inv;
        xs[r][c4 + 2] = v.z * inv;
        xs[r][c4 + 3] = v.w * inv;
    }
    int oc = t & 31;          // base output col; this thread computes oc, oc+32, oc+64, oc+96
    int r  = t >> 5;          // row within tile
    float acc0 = b[oc], acc1 = b[oc + 32], acc2 = b[oc + 64], acc3 = b[oc + 96];
    for (int h = 0; h < 2; ++h) {
        __syncthreads();      // xs ready (h=0) / everyone done reading Wl (h=1)
        // stage W[:, h*64 : h*64+64] -> Wl[128][64]
        for (int q = 0; q < 8; ++q) {
            int lin = (q * 256 + t) * 4;   // 0..32764
            int o = lin >> 6;
            int i = lin & 63;
            float4 wv = *reinterpret_cast<const float4*>(&W[o * FD + h * 64 + i]);
            Wl[o][i + 0] = wv.x;
            Wl[o][i + 1] = wv.y;
            Wl[o][i + 2] = wv.z;
            Wl[o][i + 3] = wv.w;
        }
        __syncthreads();
        for (int i = 0; i < 64; ++i) {
            float xv = xs[r][h * 64 + i];
            acc0 += xv * Wl[oc][i];
            acc1 += xv * Wl[oc + 32][i];
            acc2 += xv * Wl[oc + 64][i];
            acc3 += xv * Wl[oc + 96][i];
        }
    }
    __syncthreads();
    int row = row0 + r;
    if (row < N) {
        long long base = (long long)row * FD;
        xio[base + oc]      = fmaxf(acc0, 0.f);
        xio[base + oc + 32] = fmaxf(acc1, 0.f);
        xio[base + oc + 64] = fmaxf(acc2, 0.f);
        xio[base + oc + 96] = fmaxf(acc3, 0.f);
    }
}

// ------- attention mix: out[n,:] = sum_p softmax_p(dot(s_p[n,:],att[p,:])) * s_p[n,:] -------
__global__ __launch_bounds__(128) void k_att(const float* __restrict__ s0, const float* __restrict__ s1,
                                             const float* __restrict__ s2, const float* __restrict__ s3,
                                             const float* __restrict__ s4, const float* __restrict__ attv,
                                             float* __restrict__ out, int N0) {
    int n = blockIdx.x;
    int d = threadIdx.x;
    long long base = (long long)n * FD + d;
    float a0 = s0[base], a1 = s1[base], a2 = s2[base], a3 = s3[base], a4 = s4[base];
    float p0 = a0 * attv[0 * FD + d];
    float p1 = a1 * attv[1 * FD + d];
    float p2 = a2 * attv[2 * FD + d];
    float p3 = a3 * attv[3 * FD + d];
    float p4 = a4 * attv[4 * FD + d];
    __shared__ float red[5][2];
    int lane = d & 63, wv = d >> 6;
    float part[5] = {p0, p1, p2, p3, p4};
#pragma unroll
    for (int p = 0; p < 5; ++p) {
        float v = part[p];
#pragma unroll
        for (int off = 32; off >= 1; off >>= 1) v += __shfl_down(v, off);
        if (lane == 0) red[p][wv] = v;
    }
    __syncthreads();
    float sc[5], m = -1e30f, ssum = 0.f;
#pragma unroll
    for (int p = 0; p < 5; ++p) { sc[p] = red[p][0] + red[p][1]; m = fmaxf(m, sc[p]); }
#pragma unroll
    for (int p = 0; p < 5; ++p) { sc[p] = __expf(sc[p] - m); ssum += sc[p]; }
    float inv = 1.0f / ssum;
    out[base] = (a0 * sc[0] + a1 * sc[1] + a2 * sc[2] + a3 * sc[3] + a4 * sc[4]) * inv;
}

extern "C" void kernel_launch(void* const* d_in, const int* in_sizes, int n_in,
                              void* d_out, int out_size, void* d_ws, size_t ws_size,
                              hipStream_t stream) {
    const float* x_node = (const float*)d_in[0];
    const float* x1 = (const float*)d_in[1];
    const float* x2 = (const float*)d_in[2];
    const float* x3 = (const float*)d_in[3];
    const float* w1 = (const float*)d_in[4];
    const float* w2 = (const float*)d_in[5];
    const float* w3 = (const float*)d_in[6];
    const float* W1 = (const float*)d_in[7];
    const float* b1 = (const float*)d_in[8];
    const float* W2 = (const float*)d_in[9];
    const float* b2 = (const float*)d_in[10];
    const float* W3 = (const float*)d_in[11];
    const float* b3 = (const float*)d_in[12];
    const float* W121 = (const float*)d_in[13];
    const float* b121 = (const float*)d_in[14];
    const float* W131 = (const float*)d_in[15];
    const float* b131 = (const float*)d_in[16];
    const float* attv = (const float*)d_in[17];
    const int* e1s = (const int*)d_in[18];
    const int* e1d = (const int*)d_in[19];
    const int* e2s = (const int*)d_in[20];
    const int* e2d = (const int*)d_in[21];
    const int* e3s = (const int*)d_in[22];
    const int* e3d = (const int*)d_in[23];
    const int* e12s = (const int*)d_in[24];
    const int* e12d = (const int*)d_in[25];
    const int* e13s = (const int*)d_in[26];
    const int* e13d = (const int*)d_in[27];

    const int N0 = in_sizes[0] / FD;
    const int N1 = in_sizes[1] / FD;
    const int N2 = in_sizes[2] / FD;
    const int N3 = in_sizes[3] / FD;
    const int E = in_sizes[4];
    const int E12 = in_sizes[24];

    // ---------------- workspace layout (floats) ----------------
    float* ws = (float*)d_ws;
    size_t off = 0;
    float* s1s = ws + off;  off += (size_t)N0 * FD;
    float* s2s = ws + off;  off += (size_t)N0 * FD;
    float* s3s = ws + off;  off += (size_t)N0 * FD;
    float* s121 = ws + off; off += (size_t)N0 * FD;
    float* s131 = ws + off; off += (size_t)N0 * FD;
    float* net1 = ws + off; off += (size_t)N1 * FD;
    int NA = (N2 > N3) ? N2 : N3;            // netA: msg2/net2, later m2 (N2 or N3)
    float* netA = ws + off; off += (size_t)NA * FD;
    int NB = (N1 > N3) ? N1 : N3;            // netB: msg3/net3 (N3), later m3 (N1)
    float* netB = ws + off; off += (size_t)NB * FD;
    float* cnt1d = ws + off; off += N1;
    float* cnt2d = ws + off; off += N2;
    float* cnt3d = ws + off; off += N3;
    float* cnt1s = ws + off; off += N0;
    float* cnt2s = ws + off; off += N0;
    float* cnt3s = ws + off; off += N0;
    float* cnt12d = ws + off; off += N2;
    float* cnt12s = ws + off; off += N1;
    float* cnt13d = ws + off; off += N3;
    float* cnt13s = ws + off; off += N1;
    // (off*4 bytes ~ 168 MB; assumed <= ws_size)

    hipMemsetAsync(d_ws, 0, off * sizeof(float), stream);

    const int TB = 256;
    auto cdiv = [](long long a, long long b) { return (int)((a + b - 1) / b); };

    // ---------------- degree counts ----------------
    k_count<<<cdiv(E, TB), TB, 0, stream>>>(e1d, cnt1d, E);
    k_count<<<cdiv(E, TB), TB, 0, stream>>>(e2d, cnt2d, E);
    k_count<<<cdiv(E, TB), TB, 0, stream>>>(e3d, cnt3d, E);
    k_count<<<cdiv(E, TB), TB, 0, stream>>>(e1s, cnt1s, E);
    k_count<<<cdiv(E, TB), TB, 0, stream>>>(e2s, cnt2s, E);
    k_count<<<cdiv(E, TB), TB, 0, stream>>>(e3s, cnt3s, E);
    k_count<<<cdiv(E12, TB), TB, 0, stream>>>(e12d, cnt12d, E12);
    k_count<<<cdiv(E12, TB), TB, 0, stream>>>(e12s, cnt12s, E12);
    k_count<<<cdiv(E12, TB), TB, 0, stream>>>(e13d, cnt13d, E12);
    k_count<<<cdiv(E12, TB), TB, 0, stream>>>(e13s, cnt13s, E12);

    const int scatE = cdiv((long long)E * 32, TB);
    const int scatE12 = cdiv((long long)E12 * 32, TB);

    // ---------------- msg -> net (paths 1,2,3) ----------------
    k_scatter<<<scatE, TB, 0, stream>>>(x_node, w1, e1s, e1d, net1, E);
    k_scatter<<<scatE, TB, 0, stream>>>(x_node, w2, e2s, e2d, netA, E);
    k_scatter<<<scatE, TB, 0, stream>>>(x_node, w3, e3s, e3d, netB, E);
    k_combine<<<cdiv((long long)N1 * 32, TB), TB, 0, stream>>>(net1, cnt1d, x1, N1);
    k_combine<<<cdiv((long long)N2 * 32, TB), TB, 0, stream>>>(netA, cnt2d, x2, N2);
    k_combine<<<cdiv((long long)N3 * 32, TB), TB, 0, stream>>>(netB, cnt3d, x3, N3);

    // ---------------- short-path back-scatter + lin_relu ----------------
    k_scatter<<<scatE, TB, 0, stream>>>(net1, nullptr, e1d, e1s, s1s, E);
    k_scatter<<<scatE, TB, 0, stream>>>(netA, nullptr, e2d, e2s, s2s, E);
    k_scatter<<<scatE, TB, 0, stream>>>(netB, nullptr, e3d, e3s, s3s, E);
    k_linrelu<<<cdiv(N0, 8), 256, 0, stream>>>(s1s, cnt1s, W1, b1, N0);
    k_linrelu<<<cdiv(N0, 8), 256, 0, stream>>>(s2s, cnt2s, W2, b2, N0);
    k_linrelu<<<cdiv(N0, 8), 256, 0, stream>>>(s3s, cnt3s, W3, b3, N0);

    // ---------------- long path s-1-2-1-s ----------------
    hipMemsetAsync(netA, 0, (size_t)N2 * FD * sizeof(float), stream);
    hipMemsetAsync(netB, 0, (size_t)N1 * FD * sizeof(float), stream);
    k_scatter<<<scatE12, TB, 0, stream>>>(net1, nullptr, e12s, e12d, netA, E12);   // m2
    k_combine<<<cdiv((long long)N2 * 32, TB), TB, 0, stream>>>(netA, cnt12d, x2, N2); // n2
    k_scatter<<<scatE12, TB, 0, stream>>>(netA, nullptr, e12d, e12s, netB, E12);   // m3
    k_combine<<<cdiv((long long)N1 * 32, TB), TB, 0, stream>>>(netB, cnt12s, x1, N1); // n3
    k_scatter<<<scatE, TB, 0, stream>>>(netB, w1, e1d, e1s, s121, E);              // final
    k_linrelu<<<cdiv(N0, 8), 256, 0, stream>>>(s121, cnt1s, W121, b121, N0);

    // ---------------- long path s-1-3-1-s ----------------
    hipMemsetAsync(netA, 0, (size_t)N3 * FD * sizeof(float), stream);
    hipMemsetAsync(netB, 0, (size_t)N1 * FD * sizeof(float), stream);
    k_scatter<<<scatE12, TB, 0, stream>>>(net1, nullptr, e13s, e13d, netA, E12);   // m2
    k_combine<<<cdiv((long long)N3 * 32, TB), TB, 0, stream>>>(netA, cnt13d, x3, N3); // n2
    k_scatter<<<scatE12, TB, 0, stream>>>(netA, nullptr, e13d, e13s, netB, E12);   // m3
    k_combine<<<cdiv((long long)N1 * 32, TB), TB, 0, stream>>>(netB, cnt13s, x1, N1); // n3
    k_scatter<<<scatE, TB, 0, stream>>>(netB, w1, e1d, e1s, s131, E);              // final
    k_linrelu<<<cdiv(N0, 8), 256, 0, stream>>>(s131, cnt1s, W131, b131, N0);

    // ---------------- attention mix ----------------
    k_att<<<N0, FD, 0, stream>>>(s1s, s2s, s3s, s121, s131, attv, (float*)d_out, N0);
}

// Round 4
// 4085.522 us; speedup vs baseline: 4.0506x; 4.0506x over previous
//
#include <hip/hip_runtime.h>
#include <cmath>

static constexpr int FD = 128;

// ---------------- degree histogram: deg[idx[e]] += 1 ----------------
__global__ void k_hist(const int* __restrict__ idx, int* __restrict__ deg, int E) {
    int e = blockIdx.x * blockDim.x + threadIdx.x;
    if (e < E) atomicAdd(&deg[idx[e]], 1);
}

// ---------------- multi-CSR exclusive scan (one block per CSR) ----------------
struct ScanArgs {
    const int* deg[10];
    int* rowptr[10];
    int* cursor[10];
    int N[10];
};

__global__ __launch_bounds__(1024) void k_scan(ScanArgs a) {
    const int which = blockIdx.x;
    const int* deg = a.deg[which];
    int* rowptr = a.rowptr[which];
    int* cursor = a.cursor[which];
    const int N = a.N[which];
    __shared__ int wsum[16];
    __shared__ int carry_s;
    int t = threadIdx.x, lane = t & 63, wid = t >> 6;
    if (t == 0) { carry_s = 0; rowptr[0] = 0; }
    __syncthreads();
    for (int base = 0; base < N; base += 1024) {
        int i = base + t;
        int v = (i < N) ? deg[i] : 0;
        int s = v;
#pragma unroll
        for (int off = 1; off < 64; off <<= 1) {
            int u = __shfl_up(s, off);
            if (lane >= off) s += u;
        }
        __syncthreads();                    // (A) protect wsum/carry from prev iter
        if (lane == 63) wsum[wid] = s;
        __syncthreads();                    // (B)
        if (wid == 0) {
            int ws = (lane < 16) ? wsum[lane] : 0;
#pragma unroll
            for (int off = 1; off < 16; off <<= 1) {
                int u = __shfl_up(ws, off);
                if (lane >= off) ws += u;
            }
            if (lane < 16) wsum[lane] = ws;
        }
        __syncthreads();                    // (C)
        int waveoff = wid ? wsum[wid - 1] : 0;
        int total = wsum[15];
        int mycarry = carry_s;
        int incl = mycarry + waveoff + s;
        if (i < N) {
            rowptr[i + 1] = incl;
            cursor[i] = incl - v;           // exclusive prefix = row start
        }
        __syncthreads();                    // (D)
        if (t == 0) carry_s = mycarry + total;
    }
}

// ---------------- CSR fill: place (src, w) at cursor[dst[e]]++ ----------------
__global__ void k_fill(const int* __restrict__ dst, const int* __restrict__ src,
                       const float* __restrict__ w, int* __restrict__ cursor,
                       int* __restrict__ csr_src, float* __restrict__ csr_w, int E) {
    int e = blockIdx.x * blockDim.x + threadIdx.x;
    if (e >= E) return;
    int pos = atomicAdd(&cursor[dst[e]], 1);
    csr_src[pos] = src[e];
    if (csr_w) csr_w[pos] = w[e];
}

// ---------------- CSR gather-mean (+ optional weight, optional combine) ----------------
// One 64-lane wave per output row; lane holds cols [2*lane, 2*lane+1].
// out[n] = mean_e(feat[csr_src[e]] * w[e]); if combine: out[n] = (mean + xm[n]) * 0.5
__global__ __launch_bounds__(256) void k_gather(const float* __restrict__ feat,
                                                const int* __restrict__ csr_src,
                                                const float* __restrict__ csr_w,
                                                const int* __restrict__ rowptr,
                                                const float* __restrict__ xm,
                                                float* __restrict__ out, int N) {
    int n = blockIdx.x * 4 + (threadIdx.x >> 6);
    if (n >= N) return;
    int lane = threadIdx.x & 63;
    int start = rowptr[n], end = rowptr[n + 1];
    float2 acc = make_float2(0.f, 0.f);
    for (int base = start; base < end; base += 64) {
        int cnt = min(64, end - base);
        int myi = (base + lane < end) ? csr_src[base + lane] : 0;
        float myw = 0.0f;
        if (csr_w) myw = (base + lane < end) ? csr_w[base + lane] : 0.0f;
        for (int k = 0; k < cnt; ++k) {
            int s = __shfl(myi, k);
            const float2 v = *reinterpret_cast<const float2*>(&feat[(long long)s * FD + lane * 2]);
            float w = csr_w ? __shfl(myw, k) : 1.0f;
            acc.x += v.x * w;
            acc.y += v.y * w;
        }
    }
    float inv = 1.0f / fmaxf((float)(end - start), 1.0f);
    long long o = (long long)n * FD + lane * 2;
    float2 r;
    if (xm) {
        const float2 x = *reinterpret_cast<const float2*>(&xm[o]);
        r.x = (acc.x * inv + x.x) * 0.5f;
        r.y = (acc.y * inv + x.y) * 0.5f;
    } else {
        r.x = acc.x * inv;
        r.y = acc.y * inv;
    }
    *reinterpret_cast<float2*>(&out[o]) = r;
}

// ------- lin_relu in-place: xio[n,:] = relu(xio[n,:] @ W^T + b) -------
__global__ __launch_bounds__(256) void k_linrelu(float* __restrict__ xio,
                                                 const float* __restrict__ W,
                                                 const float* __restrict__ b, int N) {
    __shared__ float xs[8][129];
    __shared__ float Wl[128][65];
    int t = threadIdx.x;
    int row0 = blockIdx.x * 8;
    {
        int r = t >> 5, c4 = (t & 31) * 4;
        int row = row0 + r;
        float4 v = make_float4(0.f, 0.f, 0.f, 0.f);
        if (row < N) v = *reinterpret_cast<const float4*>(&xio[(long long)row * FD + c4]);
        xs[r][c4 + 0] = v.x;
        xs[r][c4 + 1] = v.y;
        xs[r][c4 + 2] = v.z;
        xs[r][c4 + 3] = v.w;
    }
    int oc = t & 31;
    int r  = t >> 5;
    float acc0 = b[oc], acc1 = b[oc + 32], acc2 = b[oc + 64], acc3 = b[oc + 96];
    for (int h = 0; h < 2; ++h) {
        __syncthreads();
        for (int q = 0; q < 8; ++q) {
            int lin = (q * 256 + t) * 4;
            int o = lin >> 6;
            int i = lin & 63;
            float4 wv = *reinterpret_cast<const float4*>(&W[o * FD + h * 64 + i]);
            Wl[o][i + 0] = wv.x;
            Wl[o][i + 1] = wv.y;
            Wl[o][i + 2] = wv.z;
            Wl[o][i + 3] = wv.w;
        }
        __syncthreads();
        for (int i = 0; i < 64; ++i) {
            float xv = xs[r][h * 64 + i];
            acc0 += xv * Wl[oc][i];
            acc1 += xv * Wl[oc + 32][i];
            acc2 += xv * Wl[oc + 64][i];
            acc3 += xv * Wl[oc + 96][i];
        }
    }
    __syncthreads();
    int row = row0 + r;
    if (row < N) {
        long long base = (long long)row * FD;
        xio[base + oc]      = fmaxf(acc0, 0.f);
        xio[base + oc + 32] = fmaxf(acc1, 0.f);
        xio[base + oc + 64] = fmaxf(acc2, 0.f);
        xio[base + oc + 96] = fmaxf(acc3, 0.f);
    }
}

// ------- attention mix -------
__global__ __launch_bounds__(128) void k_att(const float* __restrict__ s0, const float* __restrict__ s1,
                                             const float* __restrict__ s2, const float* __restrict__ s3,
                                             const float* __restrict__ s4, const float* __restrict__ attv,
                                             float* __restrict__ out, int N0) {
    int n = blockIdx.x;
    int d = threadIdx.x;
    long long base = (long long)n * FD + d;
    float a0 = s0[base], a1 = s1[base], a2 = s2[base], a3 = s3[base], a4 = s4[base];
    float part[5];
    part[0] = a0 * attv[0 * FD + d];
    part[1] = a1 * attv[1 * FD + d];
    part[2] = a2 * attv[2 * FD + d];
    part[3] = a3 * attv[3 * FD + d];
    part[4] = a4 * attv[4 * FD + d];
    __shared__ float red[5][2];
    int lane = d & 63, wv = d >> 6;
#pragma unroll
    for (int p = 0; p < 5; ++p) {
        float v = part[p];
#pragma unroll
        for (int off = 32; off >= 1; off >>= 1) v += __shfl_down(v, off);
        if (lane == 0) red[p][wv] = v;
    }
    __syncthreads();
    float sc[5], m = -1e30f, ssum = 0.f;
#pragma unroll
    for (int p = 0; p < 5; ++p) { sc[p] = red[p][0] + red[p][1]; m = fmaxf(m, sc[p]); }
#pragma unroll
    for (int p = 0; p < 5; ++p) { sc[p] = __expf(sc[p] - m); ssum += sc[p]; }
    float inv = 1.0f / ssum;
    out[base] = (a0 * sc[0] + a1 * sc[1] + a2 * sc[2] + a3 * sc[3] + a4 * sc[4]) * inv;
}

extern "C" void kernel_launch(void* const* d_in, const int* in_sizes, int n_in,
                              void* d_out, int out_size, void* d_ws, size_t ws_size,
                              hipStream_t stream) {
    const float* x_node = (const float*)d_in[0];
    const float* x1 = (const float*)d_in[1];
    const float* x2 = (const float*)d_in[2];
    const float* x3 = (const float*)d_in[3];
    const float* w1 = (const float*)d_in[4];
    const float* w2 = (const float*)d_in[5];
    const float* w3 = (const float*)d_in[6];
    const float* W1 = (const float*)d_in[7];
    const float* b1 = (const float*)d_in[8];
    const float* W2 = (const float*)d_in[9];
    const float* b2 = (const float*)d_in[10];
    const float* W3 = (const float*)d_in[11];
    const float* b3 = (const float*)d_in[12];
    const float* W121 = (const float*)d_in[13];
    const float* b121 = (const float*)d_in[14];
    const float* W131 = (const float*)d_in[15];
    const float* b131 = (const float*)d_in[16];
    const float* attv = (const float*)d_in[17];
    const int* e1s = (const int*)d_in[18];
    const int* e1d = (const int*)d_in[19];
    const int* e2s = (const int*)d_in[20];
    const int* e2d = (const int*)d_in[21];
    const int* e3s = (const int*)d_in[22];
    const int* e3d = (const int*)d_in[23];
    const int* e12s = (const int*)d_in[24];
    const int* e12d = (const int*)d_in[25];
    const int* e13s = (const int*)d_in[26];
    const int* e13d = (const int*)d_in[27];

    const int N0 = in_sizes[0] / FD;
    const int N1 = in_sizes[1] / FD;
    const int N2 = in_sizes[2] / FD;
    const int N3 = in_sizes[3] / FD;
    const int E = in_sizes[4];
    const int E12 = in_sizes[24];

    // ---------------- workspace layout ----------------
    char* wsb = (char*)d_ws;
    size_t off = 0;
    auto alloc_f = [&](size_t n) { float* p = (float*)(wsb + off); off += n * 4; return p; };
    auto alloc_i = [&](size_t n) { int* p = (int*)(wsb + off); off += n * 4; return p; };

    float* s1s  = alloc_f((size_t)N0 * FD);
    float* s2s  = alloc_f((size_t)N0 * FD);
    float* s3s  = alloc_f((size_t)N0 * FD);
    float* s121 = alloc_f((size_t)N0 * FD);
    float* s131 = alloc_f((size_t)N0 * FD);
    float* net1 = alloc_f((size_t)N1 * FD);
    int NA = (N2 > N3) ? N2 : N3;
    int NB = (N1 > N3) ? N1 : N3;
    float* netA = alloc_f((size_t)NA * FD);
    float* netB = alloc_f((size_t)NB * FD);

    // CSR order: 0:e1d(N1,E,w1) 1:e2d(N2,E,w2) 2:e3d(N3,E,w3) 3:e1s(N0,E,w1)
    //            4:e2s(N0,E) 5:e3s(N0,E) 6:e12d(N2,E12) 7:e12s(N1,E12)
    //            8:e13d(N3,E12) 9:e13s(N1,E12)
    const int   csrN[10]  = {N1, N2, N3, N0, N0, N0, N2, N1, N3, N1};
    const int   csrE[10]  = {E, E, E, E, E, E, E12, E12, E12, E12};
    const int*  csrKey[10] = {e1d, e2d, e3d, e1s, e2s, e3s, e12d, e12s, e13d, e13s};
    const int*  csrVal[10] = {e1s, e2s, e3s, e1d, e2d, e3d, e12s, e12d, e13s, e13d};
    const float* csrWin[10] = {w1, w2, w3, w1, nullptr, nullptr, nullptr, nullptr, nullptr, nullptr};

    size_t degBytesStart = off;
    int* deg[10]; int* rowptr[10]; int* cursor[10];
    for (int c = 0; c < 10; ++c) deg[c] = alloc_i(csrN[c]);
    size_t degBytes = off - degBytesStart;
    for (int c = 0; c < 10; ++c) rowptr[c] = alloc_i(csrN[c] + 1);
    for (int c = 0; c < 10; ++c) cursor[c] = alloc_i(csrN[c]);
    int* csrsrc[10]; float* csrw[10];
    for (int c = 0; c < 10; ++c) csrsrc[c] = alloc_i(csrE[c]);
    for (int c = 0; c < 10; ++c) csrw[c] = csrWin[c] ? alloc_f(csrE[c]) : nullptr;
    // total ~209 MB

    const int TB = 256;
    auto cdiv = [](long long a, long long b) { return (int)((a + b - 1) / b); };

    // ---------------- build CSRs ----------------
    hipMemsetAsync((void*)deg[0], 0, degBytes, stream);
    for (int c = 0; c < 10; ++c)
        k_hist<<<cdiv(csrE[c], TB), TB, 0, stream>>>(csrKey[c], deg[c], csrE[c]);
    ScanArgs sa;
    for (int c = 0; c < 10; ++c) { sa.deg[c] = deg[c]; sa.rowptr[c] = rowptr[c]; sa.cursor[c] = cursor[c]; sa.N[c] = csrN[c]; }
    k_scan<<<10, 1024, 0, stream>>>(sa);
    for (int c = 0; c < 10; ++c)
        k_fill<<<cdiv(csrE[c], TB), TB, 0, stream>>>(csrKey[c], csrVal[c], csrWin[c],
                                                     cursor[c], csrsrc[c], csrw[c], csrE[c]);

    auto gather = [&](const float* feat, int c, bool useW, const float* xm, float* out, int N) {
        k_gather<<<cdiv(N, 4), 256, 0, stream>>>(feat, csrsrc[c], useW ? csrw[c] : nullptr,
                                                 rowptr[c], xm, out, N);
    };

    // ---------------- shared first hop + short paths ----------------
    gather(x_node, 0, true, x1, net1, N1);       // net1 = (scatter_mean(x_node[e1s]*w1, e1d) + x1)*0.5
    gather(x_node, 1, true, x2, netA, N2);       // net2
    gather(x_node, 2, true, x3, netB, N3);       // net3
    gather(net1, 3, false, nullptr, s1s, N0);    // s1s = scatter_mean(net1[e1d], e1s)
    gather(netA, 4, false, nullptr, s2s, N0);
    gather(netB, 5, false, nullptr, s3s, N0);
    k_linrelu<<<cdiv(N0, 8), 256, 0, stream>>>(s1s, W1, b1, N0);
    k_linrelu<<<cdiv(N0, 8), 256, 0, stream>>>(s2s, W2, b2, N0);
    k_linrelu<<<cdiv(N0, 8), 256, 0, stream>>>(s3s, W3, b3, N0);

    // ---------------- long path s-1-2-1-s ----------------
    gather(net1, 6, false, x2, netA, N2);        // n2 = (scatter_mean(net1[e12s], e12d) + x2)*0.5
    gather(netA, 7, false, x1, netB, N1);        // n3 = (scatter_mean(n2[e12d], e12s) + x1)*0.5
    gather(netB, 3, true, nullptr, s121, N0);    // scatter_mean(n3[e1d]*w1, e1s)
    k_linrelu<<<cdiv(N0, 8), 256, 0, stream>>>(s121, W121, b121, N0);

    // ---------------- long path s-1-3-1-s ----------------
    gather(net1, 8, false, x3, netA, N3);
    gather(netA, 9, false, x1, netB, N1);
    gather(netB, 3, true, nullptr, s131, N0);
    k_linrelu<<<cdiv(N0, 8), 256, 0, stream>>>(s131, W131, b131, N0);

    // ---------------- attention mix ----------------
    k_att<<<N0, FD, 0, stream>>>(s1s, s2s, s3s, s121, s131, attv, (float*)d_out, N0);
}

// Round 7
// 1820.236 us; speedup vs baseline: 9.0915x; 2.2445x over previous
//
#include <hip/hip_runtime.h>
#include <cmath>

static constexpr int FD = 128;

// ---------------- degree histogram: deg[idx[e]] += 1 ----------------
__global__ void k_hist(const int* __restrict__ idx, int* __restrict__ deg, int E) {
    int e = blockIdx.x * blockDim.x + threadIdx.x;
    if (e < E) atomicAdd(&deg[idx[e]], 1);
}

// ---------------- multi-CSR exclusive scan (one block per CSR) ----------------
struct ScanArgs {
    const int* deg[10];
    int* rowptr[10];
    int* cursor[10];
    int N[10];
};

__global__ __launch_bounds__(1024) void k_scan(ScanArgs a) {
    const int which = blockIdx.x;
    const int* deg = a.deg[which];
    int* rowptr = a.rowptr[which];
    int* cursor = a.cursor[which];
    const int N = a.N[which];
    __shared__ int wsum[16];
    __shared__ int carry_s;
    int t = threadIdx.x, lane = t & 63, wid = t >> 6;
    if (t == 0) { carry_s = 0; rowptr[0] = 0; }
    __syncthreads();
    for (int base = 0; base < N; base += 1024) {
        int i = base + t;
        int v = (i < N) ? deg[i] : 0;
        int s = v;
#pragma unroll
        for (int off = 1; off < 64; off <<= 1) {
            int u = __shfl_up(s, off);
            if (lane >= off) s += u;
        }
        __syncthreads();                    // (A)
        if (lane == 63) wsum[wid] = s;
        __syncthreads();                    // (B)
        if (wid == 0) {
            int ws = (lane < 16) ? wsum[lane] : 0;
#pragma unroll
            for (int off = 1; off < 16; off <<= 1) {
                int u = __shfl_up(ws, off);
                if (lane >= off) ws += u;
            }
            if (lane < 16) wsum[lane] = ws;
        }
        __syncthreads();                    // (C)
        int waveoff = wid ? wsum[wid - 1] : 0;
        int total = wsum[15];
        int mycarry = carry_s;
        int incl = mycarry + waveoff + s;
        if (i < N) {
            rowptr[i + 1] = incl;
            cursor[i] = incl - v;
        }
        __syncthreads();                    // (D)
        if (t == 0) carry_s = mycarry + total;
    }
}

// ---------------- CSR fill: place (src, w) at cursor[dst[e]]++ ----------------
__global__ void k_fill(const int* __restrict__ dst, const int* __restrict__ src,
                       const float* __restrict__ w, int* __restrict__ cursor,
                       int* __restrict__ csr_src, float* __restrict__ csr_w, int E) {
    int e = blockIdx.x * blockDim.x + threadIdx.x;
    if (e >= E) return;
    int pos = atomicAdd(&cursor[dst[e]], 1);
    csr_src[pos] = src[e];
    if (csr_w) csr_w[pos] = w[e];
}

// ---------------- CSR gather-mean (+ optional weight, optional combine) ----------------
__global__ __launch_bounds__(256) void k_gather(const float* __restrict__ feat,
                                                const int* __restrict__ csr_src,
                                                const float* __restrict__ csr_w,
                                                const int* __restrict__ rowptr,
                                                const float* __restrict__ xm,
                                                float* __restrict__ out, int N) {
    int n = blockIdx.x * 4 + (threadIdx.x >> 6);
    if (n >= N) return;
    int lane = threadIdx.x & 63;
    int start = rowptr[n], end = rowptr[n + 1];
    float2 acc = make_float2(0.f, 0.f);
    for (int base = start; base < end; base += 64) {
        int cnt = min(64, end - base);
        int myi = (base + lane < end) ? csr_src[base + lane] : 0;
        float myw = 0.0f;
        if (csr_w) myw = (base + lane < end) ? csr_w[base + lane] : 0.0f;
        for (int k = 0; k < cnt; ++k) {
            int s = __shfl(myi, k);
            const float2 v = *reinterpret_cast<const float2*>(&feat[(long long)s * FD + lane * 2]);
            float w = csr_w ? __shfl(myw, k) : 1.0f;
            acc.x += v.x * w;
            acc.y += v.y * w;
        }
    }
    float inv = 1.0f / fmaxf((float)(end - start), 1.0f);
    long long o = (long long)n * FD + lane * 2;
    float2 r;
    if (xm) {
        const float2 x = *reinterpret_cast<const float2*>(&xm[o]);
        r.x = (acc.x * inv + x.x) * 0.5f;
        r.y = (acc.y * inv + x.y) * 0.5f;
    } else {
        r.x = acc.x * inv;
        r.y = acc.y * inv;
    }
    *reinterpret_cast<float2*>(&out[o]) = r;
}

// ------- lin_relu v2, in-place: xio[n,:] = relu(xio[n,:] @ W^T + b) -------
// Grid-stride over 32-row tiles; W staged to LDS ONCE per block (chunk-XOR
// swizzled so strided reads are 2-way/free); 4x4 register tile per thread.
// LDS = 64KB (W) + 16KB (xs) = 80KB -> 2 blocks/CU. Launch grid=512 => all
// blocks resident, W HBM traffic = 512*64KB = 32MB per call (was 400MB).
__global__ __launch_bounds__(256) void k_linrelu2(float* __restrict__ xio,
                                                  const float* __restrict__ W,
                                                  const float* __restrict__ b, int N) {
    __shared__ float Wl[128 * 128];   // [o][chunk-swizzled i]
    __shared__ float xs[32][128];
    const int t = threadIdx.x;
    // ---- stage W once, swizzled: element pair (i,i+1) of row o -> chunk ((i>>1)^(o&15)) ----
#pragma unroll
    for (int q = 0; q < 16; ++q) {
        int lin = (q * 256 + t) * 4;          // multiple of 4
        int o = lin >> 7;
        int i = lin & 127;
        float4 wv = *reinterpret_cast<const float4*>(&W[lin]);
        int sw = o & 15;
        int k0 = (i >> 1) ^ sw;
        int k1 = ((i >> 1) + 1) ^ sw;
        *reinterpret_cast<float2*>(&Wl[o * 128 + (k0 << 1)]) = make_float2(wv.x, wv.y);
        *reinterpret_cast<float2*>(&Wl[o * 128 + (k1 << 1)]) = make_float2(wv.z, wv.w);
    }
    const int oc = t & 31;                    // cols oc, +32, +64, +96
    const int rg = t >> 5;                    // row group: rows rg*4 .. rg*4+3
    const int sw = oc & 15;                   // same for oc+32/64/96
    float bias[4] = {b[oc], b[oc + 32], b[oc + 64], b[oc + 96]};

    const int ntiles = (N + 31) >> 5;
    for (int tile = blockIdx.x; tile < ntiles; tile += gridDim.x) {
        const int row0 = tile << 5;
        __syncthreads();                      // xs free to overwrite (also covers W stage, iter 0)
        {   // stage 32 rows: thread t -> row t>>3, cols (t&7)*16 .. +16
            int r = t >> 3;
            int c = (t & 7) * 16;
            int row = row0 + r;
            float4* dst = reinterpret_cast<float4*>(&xs[r][c]);
            if (row < N) {
                const float4* src = reinterpret_cast<const float4*>(&xio[(size_t)row * FD + c]);
                dst[0] = src[0]; dst[1] = src[1]; dst[2] = src[2]; dst[3] = src[3];
            } else {
                float4 z = make_float4(0.f, 0.f, 0.f, 0.f);
                dst[0] = z; dst[1] = z; dst[2] = z; dst[3] = z;
            }
        }
        __syncthreads();
        float acc[4][4];
#pragma unroll
        for (int j = 0; j < 4; ++j)
#pragma unroll
            for (int c = 0; c < 4; ++c) acc[j][c] = bias[c];
#pragma unroll 8
        for (int c2 = 0; c2 < 64; ++c2) {     // 8-byte input chunks
            int wcol = ((c2 ^ sw) << 1);
            float2 w0 = *reinterpret_cast<const float2*>(&Wl[(oc     ) * 128 + wcol]);
            float2 w1 = *reinterpret_cast<const float2*>(&Wl[(oc + 32) * 128 + wcol]);
            float2 w2 = *reinterpret_cast<const float2*>(&Wl[(oc + 64) * 128 + wcol]);
            float2 w3 = *reinterpret_cast<const float2*>(&Wl[(oc + 96) * 128 + wcol]);
            int xcol = c2 << 1;
            float2 x0 = *reinterpret_cast<const float2*>(&xs[rg * 4 + 0][xcol]);
            float2 x1 = *reinterpret_cast<const float2*>(&xs[rg * 4 + 1][xcol]);
            float2 x2 = *reinterpret_cast<const float2*>(&xs[rg * 4 + 2][xcol]);
            float2 x3 = *reinterpret_cast<const float2*>(&xs[rg * 4 + 3][xcol]);
            acc[0][0] += x0.x * w0.x + x0.y * w0.y;
            acc[0][1] += x0.x * w1.x + x0.y * w1.y;
            acc[0][2] += x0.x * w2.x + x0.y * w2.y;
            acc[0][3] += x0.x * w3.x + x0.y * w3.y;
            acc[1][0] += x1.x * w0.x + x1.y * w0.y;
            acc[1][1] += x1.x * w1.x + x1.y * w1.y;
            acc[1][2] += x1.x * w2.x + x1.y * w2.y;
            acc[1][3] += x1.x * w3.x + x1.y * w3.y;
            acc[2][0] += x2.x * w0.x + x2.y * w0.y;
            acc[2][1] += x2.x * w1.x + x2.y * w1.y;
            acc[2][2] += x2.x * w2.x + x2.y * w2.y;
            acc[2][3] += x2.x * w3.x + x2.y * w3.y;
            acc[3][0] += x3.x * w0.x + x3.y * w0.y;
            acc[3][1] += x3.x * w1.x + x3.y * w1.y;
            acc[3][2] += x3.x * w2.x + x3.y * w2.y;
            acc[3][3] += x3.x * w3.x + x3.y * w3.y;
        }
#pragma unroll
        for (int j = 0; j < 4; ++j) {
            int row = row0 + rg * 4 + j;
            if (row < N) {
                size_t base = (size_t)row * FD;
                xio[base + oc]      = fmaxf(acc[j][0], 0.f);
                xio[base + oc + 32] = fmaxf(acc[j][1], 0.f);
                xio[base + oc + 64] = fmaxf(acc[j][2], 0.f);
                xio[base + oc + 96] = fmaxf(acc[j][3], 0.f);
            }
        }
    }
}

// ------- attention mix -------
__global__ __launch_bounds__(128) void k_att(const float* __restrict__ s0, const float* __restrict__ s1,
                                             const float* __restrict__ s2, const float* __restrict__ s3,
                                             const float* __restrict__ s4, const float* __restrict__ attv,
                                             float* __restrict__ out, int N0) {
    int n = blockIdx.x;
    int d = threadIdx.x;
    long long base = (long long)n * FD + d;
    float a0 = s0[base], a1 = s1[base], a2 = s2[base], a3 = s3[base], a4 = s4[base];
    float part[5];
    part[0] = a0 * attv[0 * FD + d];
    part[1] = a1 * attv[1 * FD + d];
    part[2] = a2 * attv[2 * FD + d];
    part[3] = a3 * attv[3 * FD + d];
    part[4] = a4 * attv[4 * FD + d];
    __shared__ float red[5][2];
    int lane = d & 63, wv = d >> 6;
#pragma unroll
    for (int p = 0; p < 5; ++p) {
        float v = part[p];
#pragma unroll
        for (int off = 32; off >= 1; off >>= 1) v += __shfl_down(v, off);
        if (lane == 0) red[p][wv] = v;
    }
    __syncthreads();
    float sc[5], m = -1e30f, ssum = 0.f;
#pragma unroll
    for (int p = 0; p < 5; ++p) { sc[p] = red[p][0] + red[p][1]; m = fmaxf(m, sc[p]); }
#pragma unroll
    for (int p = 0; p < 5; ++p) { sc[p] = __expf(sc[p] - m); ssum += sc[p]; }
    float inv = 1.0f / ssum;
    out[base] = (a0 * sc[0] + a1 * sc[1] + a2 * sc[2] + a3 * sc[3] + a4 * sc[4]) * inv;
}

extern "C" void kernel_launch(void* const* d_in, const int* in_sizes, int n_in,
                              void* d_out, int out_size, void* d_ws, size_t ws_size,
                              hipStream_t stream) {
    const float* x_node = (const float*)d_in[0];
    const float* x1 = (const float*)d_in[1];
    const float* x2 = (const float*)d_in[2];
    const float* x3 = (const float*)d_in[3];
    const float* w1 = (const float*)d_in[4];
    const float* w2 = (const float*)d_in[5];
    const float* w3 = (const float*)d_in[6];
    const float* W1 = (const float*)d_in[7];
    const float* b1 = (const float*)d_in[8];
    const float* W2 = (const float*)d_in[9];
    const float* b2 = (const float*)d_in[10];
    const float* W3 = (const float*)d_in[11];
    const float* b3 = (const float*)d_in[12];
    const float* W121 = (const float*)d_in[13];
    const float* b121 = (const float*)d_in[14];
    const float* W131 = (const float*)d_in[15];
    const float* b131 = (const float*)d_in[16];
    const float* attv = (const float*)d_in[17];
    const int* e1s = (const int*)d_in[18];
    const int* e1d = (const int*)d_in[19];
    const int* e2s = (const int*)d_in[20];
    const int* e2d = (const int*)d_in[21];
    const int* e3s = (const int*)d_in[22];
    const int* e3d = (const int*)d_in[23];
    const int* e12s = (const int*)d_in[24];
    const int* e12d = (const int*)d_in[25];
    const int* e13s = (const int*)d_in[26];
    const int* e13d = (const int*)d_in[27];

    const int N0 = in_sizes[0] / FD;
    const int N1 = in_sizes[1] / FD;
    const int N2 = in_sizes[2] / FD;
    const int N3 = in_sizes[3] / FD;
    const int E = in_sizes[4];
    const int E12 = in_sizes[24];

    // ---------------- workspace layout ----------------
    char* wsb = (char*)d_ws;
    size_t off = 0;
    auto alloc_f = [&](size_t n) { float* p = (float*)(wsb + off); off += n * 4; return p; };
    auto alloc_i = [&](size_t n) { int* p = (int*)(wsb + off); off += n * 4; return p; };

    float* s1s  = alloc_f((size_t)N0 * FD);
    float* s2s  = alloc_f((size_t)N0 * FD);
    float* s3s  = alloc_f((size_t)N0 * FD);
    float* s121 = alloc_f((size_t)N0 * FD);
    float* s131 = alloc_f((size_t)N0 * FD);
    float* net1 = alloc_f((size_t)N1 * FD);
    int NA = (N2 > N3) ? N2 : N3;
    int NB = (N1 > N3) ? N1 : N3;
    float* netA = alloc_f((size_t)NA * FD);
    float* netB = alloc_f((size_t)NB * FD);

    const int   csrN[10]  = {N1, N2, N3, N0, N0, N0, N2, N1, N3, N1};
    const int   csrE[10]  = {E, E, E, E, E, E, E12, E12, E12, E12};
    const int*  csrKey[10] = {e1d, e2d, e3d, e1s, e2s, e3s, e12d, e12s, e13d, e13s};
    const int*  csrVal[10] = {e1s, e2s, e3s, e1d, e2d, e3d, e12s, e12d, e13s, e13d};
    const float* csrWin[10] = {w1, w2, w3, w1, nullptr, nullptr, nullptr, nullptr, nullptr, nullptr};

    size_t degBytesStart = off;
    int* deg[10]; int* rowptr[10]; int* cursor[10];
    for (int c = 0; c < 10; ++c) deg[c] = alloc_i(csrN[c]);
    size_t degBytes = off - degBytesStart;
    for (int c = 0; c < 10; ++c) rowptr[c] = alloc_i(csrN[c] + 1);
    for (int c = 0; c < 10; ++c) cursor[c] = alloc_i(csrN[c]);
    int* csrsrc[10]; float* csrw[10];
    for (int c = 0; c < 10; ++c) csrsrc[c] = alloc_i(csrE[c]);
    for (int c = 0; c < 10; ++c) csrw[c] = csrWin[c] ? alloc_f(csrE[c]) : nullptr;

    const int TB = 256;
    auto cdiv = [](long long a, long long b) { return (int)((a + b - 1) / b); };

    // ---------------- build CSRs ----------------
    hipMemsetAsync((void*)deg[0], 0, degBytes, stream);
    for (int c = 0; c < 10; ++c)
        k_hist<<<cdiv(csrE[c], TB), TB, 0, stream>>>(csrKey[c], deg[c], csrE[c]);
    ScanArgs sa;
    for (int c = 0; c < 10; ++c) { sa.deg[c] = deg[c]; sa.rowptr[c] = rowptr[c]; sa.cursor[c] = cursor[c]; sa.N[c] = csrN[c]; }
    k_scan<<<10, 1024, 0, stream>>>(sa);
    for (int c = 0; c < 10; ++c)
        k_fill<<<cdiv(csrE[c], TB), TB, 0, stream>>>(csrKey[c], csrVal[c], csrWin[c],
                                                     cursor[c], csrsrc[c], csrw[c], csrE[c]);

    auto gather = [&](const float* feat, int c, bool useW, const float* xm, float* out, int N) {
        k_gather<<<cdiv(N, 4), 256, 0, stream>>>(feat, csrsrc[c], useW ? csrw[c] : nullptr,
                                                 rowptr[c], xm, out, N);
    };
    auto linrelu = [&](float* xio, const float* W, const float* b) {
        int ntiles = (N0 + 31) >> 5;
        int grid = ntiles < 512 ? ntiles : 512;
        k_linrelu2<<<grid, 256, 0, stream>>>(xio, W, b, N0);
    };

    // ---------------- shared first hop + short paths ----------------
    gather(x_node, 0, true, x1, net1, N1);
    gather(x_node, 1, true, x2, netA, N2);
    gather(x_node, 2, true, x3, netB, N3);
    gather(net1, 3, false, nullptr, s1s, N0);
    gather(netA, 4, false, nullptr, s2s, N0);
    gather(netB, 5, false, nullptr, s3s, N0);
    linrelu(s1s, W1, b1);
    linrelu(s2s, W2, b2);
    linrelu(s3s, W3, b3);

    // ---------------- long path s-1-2-1-s ----------------
    gather(net1, 6, false, x2, netA, N2);
    gather(netA, 7, false, x1, netB, N1);
    gather(netB, 3, true, nullptr, s121, N0);
    linrelu(s121, W121, b121);

    // ---------------- long path s-1-3-1-s ----------------
    gather(net1, 8, false, x3, netA, N3);
    gather(netA, 9, false, x1, netB, N1);
    gather(netB, 3, true, nullptr, s131, N0);
    linrelu(s131, W131, b131);

    // ---------------- attention mix ----------------
    k_att<<<N0, FD, 0, stream>>>(s1s, s2s, s3s, s121, s131, attv, (float*)d_out, N0);
}

// Round 12
// 1708.512 us; speedup vs baseline: 9.6860x; 1.0654x over previous
//
#include <hip/hip_runtime.h>
#include <cmath>

static constexpr int FD = 128;
static constexpr int NCSR = 10;

// ---------------- fused degree histogram over all 10 CSRs ----------------
struct HistArgs {
    const int* key[NCSR];
    int* deg[NCSR];
    int E[NCSR];
    int blkOff[NCSR + 1];
};
__global__ __launch_bounds__(256) void k_hist_all(HistArgs a) {
    int b = blockIdx.x;
    int c = 0;
    while (b >= a.blkOff[c + 1]) ++c;
    int e = (b - a.blkOff[c]) * 256 + threadIdx.x;
    if (e < a.E[c]) atomicAdd(&a.deg[c][a.key[c][e]], 1);
}

// ---------------- multi-CSR exclusive scan (one block per CSR) ----------------
struct ScanArgs {
    const int* deg[NCSR];
    int* rowptr[NCSR];
    int* cursor[NCSR];
    int N[NCSR];
};
__global__ __launch_bounds__(1024) void k_scan(ScanArgs a) {
    const int which = blockIdx.x;
    const int* deg = a.deg[which];
    int* rowptr = a.rowptr[which];
    int* cursor = a.cursor[which];
    const int N = a.N[which];
    __shared__ int wsum[16];
    __shared__ int carry_s;
    int t = threadIdx.x, lane = t & 63, wid = t >> 6;
    if (t == 0) { carry_s = 0; rowptr[0] = 0; }
    __syncthreads();
    for (int base = 0; base < N; base += 1024) {
        int i = base + t;
        int v = (i < N) ? deg[i] : 0;
        int s = v;
#pragma unroll
        for (int off = 1; off < 64; off <<= 1) {
            int u = __shfl_up(s, off);
            if (lane >= off) s += u;
        }
        __syncthreads();                    // (A)
        if (lane == 63) wsum[wid] = s;
        __syncthreads();                    // (B)
        if (wid == 0) {
            int ws = (lane < 16) ? wsum[lane] : 0;
#pragma unroll
            for (int off = 1; off < 16; off <<= 1) {
                int u = __shfl_up(ws, off);
                if (lane >= off) ws += u;
            }
            if (lane < 16) wsum[lane] = ws;
        }
        __syncthreads();                    // (C)
        int waveoff = wid ? wsum[wid - 1] : 0;
        int total = wsum[15];
        int mycarry = carry_s;
        int incl = mycarry + waveoff + s;
        if (i < N) {
            rowptr[i + 1] = incl;
            cursor[i] = incl - v;
        }
        __syncthreads();                    // (D)
        if (t == 0) carry_s = mycarry + total;
    }
}

// ---------------- fused CSR fill over all 10 CSRs ----------------
// paired CSRs store (src, w) as int2 in one 8B scattered store.
struct FillArgs {
    const int* key[NCSR];
    const int* val[NCSR];
    const float* w[NCSR];
    int* cursor[NCSR];
    int* dst[NCSR];          // int2* when paired, int* otherwise
    int E[NCSR];
    int blkOff[NCSR + 1];
    int paired[NCSR];
};
__global__ __launch_bounds__(256) void k_fill_all(FillArgs a) {
    int b = blockIdx.x;
    int c = 0;
    while (b >= a.blkOff[c + 1]) ++c;
    int e = (b - a.blkOff[c]) * 256 + threadIdx.x;
    if (e >= a.E[c]) return;
    int pos = atomicAdd(&a.cursor[c][a.key[c][e]], 1);
    if (a.paired[c]) {
        int2 p;
        p.x = a.val[c][e];
        p.y = __float_as_int(a.w[c][e]);
        reinterpret_cast<int2*>(a.dst[c])[pos] = p;
    } else {
        a.dst[c][pos] = a.val[c][e];
    }
}

// ---------------- weighted gather-mean from paired CSR, unroll-4 ----------------
// One 64-lane wave per row; lane holds cols [2*lane, 2*lane+1].
__global__ __launch_bounds__(256) void k_gather_w(const float* __restrict__ feat,
                                                  const int2* __restrict__ pairs,
                                                  const int* __restrict__ rowptr,
                                                  const float* __restrict__ xm,
                                                  float* __restrict__ out, int N) {
    int n = blockIdx.x * 4 + (threadIdx.x >> 6);
    if (n >= N) return;
    int lane = threadIdx.x & 63;
    int start = rowptr[n], end = rowptr[n + 1];
    float2 acc = make_float2(0.f, 0.f);
    for (int base = start; base < end; base += 64) {
        int cnt = min(64, end - base);
        int2 mp = (base + lane < end) ? pairs[base + lane] : make_int2(0, 0);
        int k = 0;
        for (; k + 4 <= cnt; k += 4) {
            int s0 = __shfl(mp.x, k),     s1 = __shfl(mp.x, k + 1);
            int s2 = __shfl(mp.x, k + 2), s3 = __shfl(mp.x, k + 3);
            float w0 = __int_as_float(__shfl(mp.y, k));
            float w1 = __int_as_float(__shfl(mp.y, k + 1));
            float w2 = __int_as_float(__shfl(mp.y, k + 2));
            float w3 = __int_as_float(__shfl(mp.y, k + 3));
            float2 v0 = *reinterpret_cast<const float2*>(&feat[(size_t)s0 * FD + lane * 2]);
            float2 v1 = *reinterpret_cast<const float2*>(&feat[(size_t)s1 * FD + lane * 2]);
            float2 v2 = *reinterpret_cast<const float2*>(&feat[(size_t)s2 * FD + lane * 2]);
            float2 v3 = *reinterpret_cast<const float2*>(&feat[(size_t)s3 * FD + lane * 2]);
            acc.x += v0.x * w0 + v1.x * w1 + v2.x * w2 + v3.x * w3;
            acc.y += v0.y * w0 + v1.y * w1 + v2.y * w2 + v3.y * w3;
        }
        for (; k < cnt; ++k) {
            int s = __shfl(mp.x, k);
            float w = __int_as_float(__shfl(mp.y, k));
            float2 v = *reinterpret_cast<const float2*>(&feat[(size_t)s * FD + lane * 2]);
            acc.x += v.x * w;
            acc.y += v.y * w;
        }
    }
    float inv = 1.0f / fmaxf((float)(end - start), 1.0f);
    size_t o = (size_t)n * FD + lane * 2;
    float2 r;
    if (xm) {
        const float2 x = *reinterpret_cast<const float2*>(&xm[o]);
        r.x = (acc.x * inv + x.x) * 0.5f;
        r.y = (acc.y * inv + x.y) * 0.5f;
    } else {
        r.x = acc.x * inv;
        r.y = acc.y * inv;
    }
    *reinterpret_cast<float2*>(&out[o]) = r;
}

// ---------------- unweighted gather-mean, unroll-4 ----------------
__global__ __launch_bounds__(256) void k_gather_u(const float* __restrict__ feat,
                                                  const int* __restrict__ csr_src,
                                                  const int* __restrict__ rowptr,
                                                  const float* __restrict__ xm,
                                                  float* __restrict__ out, int N) {
    int n = blockIdx.x * 4 + (threadIdx.x >> 6);
    if (n >= N) return;
    int lane = threadIdx.x & 63;
    int start = rowptr[n], end = rowptr[n + 1];
    float2 acc = make_float2(0.f, 0.f);
    for (int base = start; base < end; base += 64) {
        int cnt = min(64, end - base);
        int myi = (base + lane < end) ? csr_src[base + lane] : 0;
        int k = 0;
        for (; k + 4 <= cnt; k += 4) {
            int s0 = __shfl(myi, k),     s1 = __shfl(myi, k + 1);
            int s2 = __shfl(myi, k + 2), s3 = __shfl(myi, k + 3);
            float2 v0 = *reinterpret_cast<const float2*>(&feat[(size_t)s0 * FD + lane * 2]);
            float2 v1 = *reinterpret_cast<const float2*>(&feat[(size_t)s1 * FD + lane * 2]);
            float2 v2 = *reinterpret_cast<const float2*>(&feat[(size_t)s2 * FD + lane * 2]);
            float2 v3 = *reinterpret_cast<const float2*>(&feat[(size_t)s3 * FD + lane * 2]);
            acc.x += v0.x + v1.x + v2.x + v3.x;
            acc.y += v0.y + v1.y + v2.y + v3.y;
        }
        for (; k < cnt; ++k) {
            int s = __shfl(myi, k);
            float2 v = *reinterpret_cast<const float2*>(&feat[(size_t)s * FD + lane * 2]);
            acc.x += v.x;
            acc.y += v.y;
        }
    }
    float inv = 1.0f / fmaxf((float)(end - start), 1.0f);
    size_t o = (size_t)n * FD + lane * 2;
    float2 r;
    if (xm) {
        const float2 x = *reinterpret_cast<const float2*>(&xm[o]);
        r.x = (acc.x * inv + x.x) * 0.5f;
        r.y = (acc.y * inv + x.y) * 0.5f;
    } else {
        r.x = acc.x * inv;
        r.y = acc.y * inv;
    }
    *reinterpret_cast<float2*>(&out[o]) = r;
}

// ---------------- fused triple gather over CSR 3 (e1s), unroll-2 ----------------
// s1s <- mean(net1[e1d])            (UNWEIGHTED — short_path back-scatter)
// s121 <- mean(n3_12[e1d] * w1)     (weighted — long-path final hop)
// s131 <- mean(n3_13[e1d] * w1)     (weighted)
__global__ __launch_bounds__(256) void k_gather3_w(const float* __restrict__ f1,
                                                   const float* __restrict__ f2,
                                                   const float* __restrict__ f3,
                                                   const int2* __restrict__ pairs,
                                                   const int* __restrict__ rowptr,
                                                   float* __restrict__ o1,
                                                   float* __restrict__ o2,
                                                   float* __restrict__ o3, int N) {
    int n = blockIdx.x * 4 + (threadIdx.x >> 6);
    if (n >= N) return;
    int lane = threadIdx.x & 63;
    int start = rowptr[n], end = rowptr[n + 1];
    float2 a1 = make_float2(0.f, 0.f), a2 = a1, a3 = a1;
    for (int base = start; base < end; base += 64) {
        int cnt = min(64, end - base);
        int2 mp = (base + lane < end) ? pairs[base + lane] : make_int2(0, 0);
        int k = 0;
        for (; k + 2 <= cnt; k += 2) {
            int sA = __shfl(mp.x, k), sB = __shfl(mp.x, k + 1);
            float wA = __int_as_float(__shfl(mp.y, k));
            float wB = __int_as_float(__shfl(mp.y, k + 1));
            size_t oA = (size_t)sA * FD + lane * 2;
            size_t oB = (size_t)sB * FD + lane * 2;
            float2 v1A = *reinterpret_cast<const float2*>(&f1[oA]);
            float2 v2A = *reinterpret_cast<const float2*>(&f2[oA]);
            float2 v3A = *reinterpret_cast<const float2*>(&f3[oA]);
            float2 v1B = *reinterpret_cast<const float2*>(&f1[oB]);
            float2 v2B = *reinterpret_cast<const float2*>(&f2[oB]);
            float2 v3B = *reinterpret_cast<const float2*>(&f3[oB]);
            a1.x += v1A.x + v1B.x;            a1.y += v1A.y + v1B.y;            // unweighted
            a2.x += v2A.x * wA + v2B.x * wB;  a2.y += v2A.y * wA + v2B.y * wB;
            a3.x += v3A.x * wA + v3B.x * wB;  a3.y += v3A.y * wA + v3B.y * wB;
        }
        for (; k < cnt; ++k) {
            int s = __shfl(mp.x, k);
            float w = __int_as_float(__shfl(mp.y, k));
            size_t oo = (size_t)s * FD + lane * 2;
            float2 v1 = *reinterpret_cast<const float2*>(&f1[oo]);
            float2 v2 = *reinterpret_cast<const float2*>(&f2[oo]);
            float2 v3 = *reinterpret_cast<const float2*>(&f3[oo]);
            a1.x += v1.x;      a1.y += v1.y;                                    // unweighted
            a2.x += v2.x * w;  a2.y += v2.y * w;
            a3.x += v3.x * w;  a3.y += v3.y * w;
        }
    }
    float inv = 1.0f / fmaxf((float)(end - start), 1.0f);
    size_t o = (size_t)n * FD + lane * 2;
    *reinterpret_cast<float2*>(&o1[o]) = make_float2(a1.x * inv, a1.y * inv);
    *reinterpret_cast<float2*>(&o2[o]) = make_float2(a2.x * inv, a2.y * inv);
    *reinterpret_cast<float2*>(&o3[o]) = make_float2(a3.x * inv, a3.y * inv);
}

// ------- lin_relu v2, in-place: xio[n,:] = relu(xio[n,:] @ W^T + b) -------
__global__ __launch_bounds__(256) void k_linrelu2(float* __restrict__ xio,
                                                  const float* __restrict__ W,
                                                  const float* __restrict__ b, int N) {
    __shared__ float Wl[128 * 128];
    __shared__ float xs[32][128];
    const int t = threadIdx.x;
#pragma unroll
    for (int q = 0; q < 16; ++q) {
        int lin = (q * 256 + t) * 4;
        int o = lin >> 7;
        int i = lin & 127;
        float4 wv = *reinterpret_cast<const float4*>(&W[lin]);
        int sw = o & 15;
        int k0 = (i >> 1) ^ sw;
        int k1 = ((i >> 1) + 1) ^ sw;
        *reinterpret_cast<float2*>(&Wl[o * 128 + (k0 << 1)]) = make_float2(wv.x, wv.y);
        *reinterpret_cast<float2*>(&Wl[o * 128 + (k1 << 1)]) = make_float2(wv.z, wv.w);
    }
    const int oc = t & 31;
    const int rg = t >> 5;
    const int sw = oc & 15;
    float bias[4] = {b[oc], b[oc + 32], b[oc + 64], b[oc + 96]};

    const int ntiles = (N + 31) >> 5;
    for (int tile = blockIdx.x; tile < ntiles; tile += gridDim.x) {
        const int row0 = tile << 5;
        __syncthreads();
        {
            int r = t >> 3;
            int c = (t & 7) * 16;
            int row = row0 + r;
            float4* dst = reinterpret_cast<float4*>(&xs[r][c]);
            if (row < N) {
                const float4* src = reinterpret_cast<const float4*>(&xio[(size_t)row * FD + c]);
                dst[0] = src[0]; dst[1] = src[1]; dst[2] = src[2]; dst[3] = src[3];
            } else {
                float4 z = make_float4(0.f, 0.f, 0.f, 0.f);
                dst[0] = z; dst[1] = z; dst[2] = z; dst[3] = z;
            }
        }
        __syncthreads();
        float acc[4][4];
#pragma unroll
        for (int j = 0; j < 4; ++j)
#pragma unroll
            for (int c = 0; c < 4; ++c) acc[j][c] = bias[c];
#pragma unroll 8
        for (int c2 = 0; c2 < 64; ++c2) {
            int wcol = ((c2 ^ sw) << 1);
            float2 w0 = *reinterpret_cast<const float2*>(&Wl[(oc     ) * 128 + wcol]);
            float2 w1 = *reinterpret_cast<const float2*>(&Wl[(oc + 32) * 128 + wcol]);
            float2 w2 = *reinterpret_cast<const float2*>(&Wl[(oc + 64) * 128 + wcol]);
            float2 w3 = *reinterpret_cast<const float2*>(&Wl[(oc + 96) * 128 + wcol]);
            int xcol = c2 << 1;
            float2 x0 = *reinterpret_cast<const float2*>(&xs[rg * 4 + 0][xcol]);
            float2 x1 = *reinterpret_cast<const float2*>(&xs[rg * 4 + 1][xcol]);
            float2 x2 = *reinterpret_cast<const float2*>(&xs[rg * 4 + 2][xcol]);
            float2 x3 = *reinterpret_cast<const float2*>(&xs[rg * 4 + 3][xcol]);
            acc[0][0] += x0.x * w0.x + x0.y * w0.y;
            acc[0][1] += x0.x * w1.x + x0.y * w1.y;
            acc[0][2] += x0.x * w2.x + x0.y * w2.y;
            acc[0][3] += x0.x * w3.x + x0.y * w3.y;
            acc[1][0] += x1.x * w0.x + x1.y * w0.y;
            acc[1][1] += x1.x * w1.x + x1.y * w1.y;
            acc[1][2] += x1.x * w2.x + x1.y * w2.y;
            acc[1][3] += x1.x * w3.x + x1.y * w3.y;
            acc[2][0] += x2.x * w0.x + x2.y * w0.y;
            acc[2][1] += x2.x * w1.x + x2.y * w1.y;
            acc[2][2] += x2.x * w2.x + x2.y * w2.y;
            acc[2][3] += x2.x * w3.x + x2.y * w3.y;
            acc[3][0] += x3.x * w0.x + x3.y * w0.y;
            acc[3][1] += x3.x * w1.x + x3.y * w1.y;
            acc[3][2] += x3.x * w2.x + x3.y * w2.y;
            acc[3][3] += x3.x * w3.x + x3.y * w3.y;
        }
#pragma unroll
        for (int j = 0; j < 4; ++j) {
            int row = row0 + rg * 4 + j;
            if (row < N) {
                size_t base = (size_t)row * FD;
                xio[base + oc]      = fmaxf(acc[j][0], 0.f);
                xio[base + oc + 32] = fmaxf(acc[j][1], 0.f);
                xio[base + oc + 64] = fmaxf(acc[j][2], 0.f);
                xio[base + oc + 96] = fmaxf(acc[j][3], 0.f);
            }
        }
    }
}

// ------- attention mix -------
__global__ __launch_bounds__(128) void k_att(const float* __restrict__ s0, const float* __restrict__ s1,
                                             const float* __restrict__ s2, const float* __restrict__ s3,
                                             const float* __restrict__ s4, const float* __restrict__ attv,
                                             float* __restrict__ out, int N0) {
    int n = blockIdx.x;
    int d = threadIdx.x;
    size_t base = (size_t)n * FD + d;
    float a0 = s0[base], a1 = s1[base], a2 = s2[base], a3 = s3[base], a4 = s4[base];
    float part[5];
    part[0] = a0 * attv[0 * FD + d];
    part[1] = a1 * attv[1 * FD + d];
    part[2] = a2 * attv[2 * FD + d];
    part[3] = a3 * attv[3 * FD + d];
    part[4] = a4 * attv[4 * FD + d];
    __shared__ float red[5][2];
    int lane = d & 63, wv = d >> 6;
#pragma unroll
    for (int p = 0; p < 5; ++p) {
        float v = part[p];
#pragma unroll
        for (int off = 32; off >= 1; off >>= 1) v += __shfl_down(v, off);
        if (lane == 0) red[p][wv] = v;
    }
    __syncthreads();
    float sc[5], m = -1e30f, ssum = 0.f;
#pragma unroll
    for (int p = 0; p < 5; ++p) { sc[p] = red[p][0] + red[p][1]; m = fmaxf(m, sc[p]); }
#pragma unroll
    for (int p = 0; p < 5; ++p) { sc[p] = __expf(sc[p] - m); ssum += sc[p]; }
    float inv = 1.0f / ssum;
    out[base] = (a0 * sc[0] + a1 * sc[1] + a2 * sc[2] + a3 * sc[3] + a4 * sc[4]) * inv;
}

extern "C" void kernel_launch(void* const* d_in, const int* in_sizes, int n_in,
                              void* d_out, int out_size, void* d_ws, size_t ws_size,
                              hipStream_t stream) {
    const float* x_node = (const float*)d_in[0];
    const float* x1 = (const float*)d_in[1];
    const float* x2 = (const float*)d_in[2];
    const float* x3 = (const float*)d_in[3];
    const float* w1 = (const float*)d_in[4];
    const float* w2 = (const float*)d_in[5];
    const float* w3 = (const float*)d_in[6];
    const float* W1 = (const float*)d_in[7];
    const float* b1 = (const float*)d_in[8];
    const float* W2 = (const float*)d_in[9];
    const float* b2 = (const float*)d_in[10];
    const float* W3 = (const float*)d_in[11];
    const float* b3 = (const float*)d_in[12];
    const float* W121 = (const float*)d_in[13];
    const float* b121 = (const float*)d_in[14];
    const float* W131 = (const float*)d_in[15];
    const float* b131 = (const float*)d_in[16];
    const float* attv = (const float*)d_in[17];
    const int* e1s = (const int*)d_in[18];
    const int* e1d = (const int*)d_in[19];
    const int* e2s = (const int*)d_in[20];
    const int* e2d = (const int*)d_in[21];
    const int* e3s = (const int*)d_in[22];
    const int* e3d = (const int*)d_in[23];
    const int* e12s = (const int*)d_in[24];
    const int* e12d = (const int*)d_in[25];
    const int* e13s = (const int*)d_in[26];
    const int* e13d = (const int*)d_in[27];

    const int N0 = in_sizes[0] / FD;
    const int N1 = in_sizes[1] / FD;
    const int N2 = in_sizes[2] / FD;
    const int N3 = in_sizes[3] / FD;
    const int E = in_sizes[4];
    const int E12 = in_sizes[24];

    // ---------------- workspace layout ----------------
    char* wsb = (char*)d_ws;
    size_t off = 0;
    auto alloc_f = [&](size_t n) { float* p = (float*)(wsb + off); off += n * 4; return p; };
    auto alloc_i = [&](size_t n) { int* p = (int*)(wsb + off); off += n * 4; return p; };

    float* s1s  = alloc_f((size_t)N0 * FD);
    float* s2s  = alloc_f((size_t)N0 * FD);
    float* s3s  = alloc_f((size_t)N0 * FD);
    float* s121 = alloc_f((size_t)N0 * FD);
    float* s131 = alloc_f((size_t)N0 * FD);
    float* net1 = alloc_f((size_t)N1 * FD);
    float* A2   = alloc_f((size_t)N2 * FD);   // net2, later m2_12
    float* A3   = alloc_f((size_t)N3 * FD);   // net3, later m2_13
    float* B12  = alloc_f((size_t)N1 * FD);   // n3 of path s-1-2-1-s
    float* B13  = alloc_f((size_t)N1 * FD);   // n3 of path s-1-3-1-s

    // CSR table: 0:e1d(N1,E,w1,P) 1:e2d(N2,E,w2,P) 2:e3d(N3,E,w3,P) 3:e1s(N0,E,w1,P)
    //            4:e2s(N0,E) 5:e3s(N0,E) 6:e12d(N2,E12) 7:e12s(N1,E12)
    //            8:e13d(N3,E12) 9:e13s(N1,E12)
    const int   csrN[NCSR]    = {N1, N2, N3, N0, N0, N0, N2, N1, N3, N1};
    const int   csrE[NCSR]    = {E, E, E, E, E, E, E12, E12, E12, E12};
    const int*  csrKey[NCSR]  = {e1d, e2d, e3d, e1s, e2s, e3s, e12d, e12s, e13d, e13s};
    const int*  csrVal[NCSR]  = {e1s, e2s, e3s, e1d, e2d, e3d, e12s, e12d, e13s, e13d};
    const float* csrWin[NCSR] = {w1, w2, w3, w1, nullptr, nullptr, nullptr, nullptr, nullptr, nullptr};

    size_t degStart = off;
    int* deg[NCSR]; int* rowptr[NCSR]; int* cursor[NCSR]; int* dst[NCSR];
    for (int c = 0; c < NCSR; ++c) deg[c] = alloc_i(csrN[c]);
    size_t degBytes = off - degStart;
    for (int c = 0; c < NCSR; ++c) rowptr[c] = alloc_i(csrN[c] + 1);
    for (int c = 0; c < NCSR; ++c) cursor[c] = alloc_i(csrN[c]);
    for (int c = 0; c < NCSR; ++c) dst[c] = alloc_i(csrWin[c] ? (size_t)csrE[c] * 2 : (size_t)csrE[c]);

    const int TB = 256;
    auto cdiv = [](long long a, long long b) { return (int)((a + b - 1) / b); };

    // ---------------- build CSRs (fused launches) ----------------
    hipMemsetAsync((void*)deg[0], 0, degBytes, stream);

    HistArgs ha;
    FillArgs fa;
    int boff = 0;
    for (int c = 0; c < NCSR; ++c) {
        ha.key[c] = csrKey[c]; ha.deg[c] = deg[c]; ha.E[c] = csrE[c];
        fa.key[c] = csrKey[c]; fa.val[c] = csrVal[c]; fa.w[c] = csrWin[c];
        fa.cursor[c] = cursor[c]; fa.dst[c] = dst[c]; fa.E[c] = csrE[c];
        fa.paired[c] = csrWin[c] ? 1 : 0;
        ha.blkOff[c] = boff; fa.blkOff[c] = boff;
        boff += cdiv(csrE[c], TB);
    }
    ha.blkOff[NCSR] = boff; fa.blkOff[NCSR] = boff;

    k_hist_all<<<boff, TB, 0, stream>>>(ha);
    ScanArgs sa;
    for (int c = 0; c < NCSR; ++c) { sa.deg[c] = deg[c]; sa.rowptr[c] = rowptr[c]; sa.cursor[c] = cursor[c]; sa.N[c] = csrN[c]; }
    k_scan<<<NCSR, 1024, 0, stream>>>(sa);
    k_fill_all<<<boff, TB, 0, stream>>>(fa);

    auto gw = [&](const float* feat, int c, const float* xm, float* out, int N) {
        k_gather_w<<<cdiv(N, 4), 256, 0, stream>>>(feat, (const int2*)dst[c], rowptr[c], xm, out, N);
    };
    auto gu = [&](const float* feat, int c, const float* xm, float* out, int N) {
        k_gather_u<<<cdiv(N, 4), 256, 0, stream>>>(feat, dst[c], rowptr[c], xm, out, N);
    };
    auto linrelu = [&](float* xio, const float* W, const float* b) {
        int ntiles = (N0 + 31) >> 5;
        int grid = ntiles < 512 ? ntiles : 512;
        k_linrelu2<<<grid, 256, 0, stream>>>(xio, W, b, N0);
    };

    // ---------------- first hop (3 weighted gathers from x_node) ----------------
    gw(x_node, 0, x1, net1, N1);      // net1
    gw(x_node, 1, x2, A2, N2);        // net2
    gw(x_node, 2, x3, A3, N3);        // net3

    // ---------------- short paths 2,3 back-gather ----------------
    gu(A2, 4, nullptr, s2s, N0);
    gu(A3, 5, nullptr, s3s, N0);

    // ---------------- long path intermediates ----------------
    gu(net1, 6, x2, A2, N2);          // m2_12 -> n2_12  (A2 reuse, prior reader done)
    gu(A2, 7, x1, B12, N1);           // n3_12
    gu(net1, 8, x3, A3, N3);          // m2_13 -> n2_13
    gu(A3, 9, x1, B13, N1);           // n3_13

    // ---------------- fused triple back-gather over CSR 3 (e1s; s1s unweighted, s121/s131 * w1) ----------------
    k_gather3_w<<<cdiv(N0, 4), 256, 0, stream>>>(net1, B12, B13, (const int2*)dst[3],
                                                 rowptr[3], s1s, s121, s131, N0);

    // ---------------- lin_relu x5 ----------------
    linrelu(s1s, W1, b1);
    linrelu(s2s, W2, b2);
    linrelu(s3s, W3, b3);
    linrelu(s121, W121, b121);
    linrelu(s131, W131, b131);

    // ---------------- attention mix ----------------
    k_att<<<N0, FD, 0, stream>>>(s1s, s2s, s3s, s121, s131, attv, (float*)d_out, N0);
}

// Round 15
// 1445.741 us; speedup vs baseline: 11.4465x; 1.1818x over previous
//
#include <hip/hip_runtime.h>
#include <cmath>

static constexpr int FD = 128;
static constexpr int NCSR = 10;
static constexpr int TILE_A = 2048;   // edges per pass-A block (8 per thread)

// ---------------- fused degree histogram over all 10 CSRs ----------------
struct HistArgs {
    const int* key[NCSR];
    int* deg[NCSR];
    int E[NCSR];
    int blkOff[NCSR + 1];
};
__global__ __launch_bounds__(256) void k_hist_all(HistArgs a) {
    int b = blockIdx.x;
    int c = 0;
    while (b >= a.blkOff[c + 1]) ++c;
    int e = (b - a.blkOff[c]) * 256 + threadIdx.x;
    if (e < a.E[c]) atomicAdd(&a.deg[c][a.key[c][e]], 1);
}

// ---------------- multi-CSR exclusive scan (one block per CSR) ----------------
// also emits per-bucket (256-row) base cursors for the binned fill.
struct ScanArgs {
    const int* deg[NCSR];
    int* rowptr[NCSR];
    int* cursor[NCSR];
    int* bcur[NCSR];
    int N[NCSR];
};
__global__ __launch_bounds__(1024) void k_scan(ScanArgs a) {
    const int which = blockIdx.x;
    const int* deg = a.deg[which];
    int* rowptr = a.rowptr[which];
    int* cursor = a.cursor[which];
    int* bcur = a.bcur[which];
    const int N = a.N[which];
    __shared__ int wsum[16];
    __shared__ int carry_s;
    int t = threadIdx.x, lane = t & 63, wid = t >> 6;
    if (t == 0) { carry_s = 0; rowptr[0] = 0; }
    __syncthreads();
    for (int base = 0; base < N; base += 1024) {
        int i = base + t;
        int v = (i < N) ? deg[i] : 0;
        int s = v;
#pragma unroll
        for (int off = 1; off < 64; off <<= 1) {
            int u = __shfl_up(s, off);
            if (lane >= off) s += u;
        }
        __syncthreads();                    // (A)
        if (lane == 63) wsum[wid] = s;
        __syncthreads();                    // (B)
        if (wid == 0) {
            int ws = (lane < 16) ? wsum[lane] : 0;
#pragma unroll
            for (int off = 1; off < 16; off <<= 1) {
                int u = __shfl_up(ws, off);
                if (lane >= off) ws += u;
            }
            if (lane < 16) wsum[lane] = ws;
        }
        __syncthreads();                    // (C)
        int waveoff = wid ? wsum[wid - 1] : 0;
        int total = wsum[15];
        int mycarry = carry_s;
        int incl = mycarry + waveoff + s;
        if (i < N) {
            int rstart = incl - v;
            rowptr[i + 1] = incl;
            cursor[i] = rstart;
            if ((i & 255) == 0) bcur[i >> 8] = rstart;
        }
        __syncthreads();                    // (D)
        if (t == 0) carry_s = mycarry + total;
    }
}

// ---------------- pass A: binned staging fill ----------------
// Per tile: LDS hist by bucket (dst>>8), reserve contiguous run per (tile,bucket)
// with ONE global atomic, write 16B records {dst, src, wbits, 0} densely.
struct BinAArgs {
    const int* key[NCSR];
    const int* val[NCSR];
    const float* w[NCSR];
    int* bcur[NCSR];
    int4* stage[NCSR];
    int E[NCSR];
    int blkOff[NCSR + 1];
    int paired[NCSR];
};
__global__ __launch_bounds__(256) void k_binA(BinAArgs a) {
    __shared__ int hist[256];
    __shared__ int lcnt[256];
    __shared__ int gbase[256];
    int b = blockIdx.x;
    int c = 0;
    while (b >= a.blkOff[c + 1]) ++c;
    int e0 = (b - a.blkOff[c]) * TILE_A;
    int t = threadIdx.x;
    int E = a.E[c];
    hist[t] = 0; lcnt[t] = 0;
    __syncthreads();
    int key[8];
#pragma unroll
    for (int k = 0; k < 8; ++k) {
        int e = e0 + k * 256 + t;
        key[k] = (e < E) ? a.key[c][e] : -1;
        if (key[k] >= 0) atomicAdd(&hist[key[k] >> 8], 1);
    }
    __syncthreads();
    if (hist[t] > 0) gbase[t] = atomicAdd(&a.bcur[c][t], hist[t]);
    __syncthreads();
    const int* val = a.val[c];
    const float* w = a.w[c];
    int4* stage = a.stage[c];
    int paired = a.paired[c];
#pragma unroll
    for (int k = 0; k < 8; ++k) {
        if (key[k] < 0) continue;
        int e = e0 + k * 256 + t;
        int bk = key[k] >> 8;
        int loff = atomicAdd(&lcnt[bk], 1);
        int4 rec;
        rec.x = key[k];
        rec.y = val[e];
        rec.z = paired ? __float_as_int(w[e]) : 0;
        rec.w = 0;
        stage[gbase[bk] + loff] = rec;
    }
}

// ---------------- pass B: per-bucket scatter to exact CSR position ----------------
struct BinBArgs {
    const int4* stage[NCSR];
    const int* rowptr[NCSR];
    int* cursor[NCSR];
    int* dst[NCSR];
    int N[NCSR];
    int blkOff[NCSR + 1];
    int paired[NCSR];
};
__global__ __launch_bounds__(256) void k_binB(BinBArgs a) {
    int b = blockIdx.x;
    int c = 0;
    while (b >= a.blkOff[c + 1]) ++c;
    int bk = b - a.blkOff[c];
    int r0 = bk << 8;
    int r1 = min(r0 + 256, a.N[c]);
    int sbeg = a.rowptr[c][r0];
    int send = a.rowptr[c][r1];
    const int4* stage = a.stage[c];
    int* cursor = a.cursor[c];
    int* dst = a.dst[c];
    int paired = a.paired[c];
    for (int s = sbeg + (int)threadIdx.x; s < send; s += 256) {
        int4 rec = stage[s];
        int pos = atomicAdd(&cursor[rec.x], 1);
        if (paired) reinterpret_cast<int2*>(dst)[pos] = make_int2(rec.y, rec.z);
        else dst[pos] = rec.y;
    }
}

// ---------------- weighted gather-mean from paired CSR, unroll-4 ----------------
__global__ __launch_bounds__(256) void k_gather_w(const float* __restrict__ feat,
                                                  const int2* __restrict__ pairs,
                                                  const int* __restrict__ rowptr,
                                                  const float* __restrict__ xm,
                                                  float* __restrict__ out, int N) {
    int n = blockIdx.x * 4 + (threadIdx.x >> 6);
    if (n >= N) return;
    int lane = threadIdx.x & 63;
    int start = rowptr[n], end = rowptr[n + 1];
    float2 acc = make_float2(0.f, 0.f);
    for (int base = start; base < end; base += 64) {
        int cnt = min(64, end - base);
        int2 mp = (base + lane < end) ? pairs[base + lane] : make_int2(0, 0);
        int k = 0;
        for (; k + 4 <= cnt; k += 4) {
            int s0 = __shfl(mp.x, k),     s1 = __shfl(mp.x, k + 1);
            int s2 = __shfl(mp.x, k + 2), s3 = __shfl(mp.x, k + 3);
            float w0 = __int_as_float(__shfl(mp.y, k));
            float w1 = __int_as_float(__shfl(mp.y, k + 1));
            float w2 = __int_as_float(__shfl(mp.y, k + 2));
            float w3 = __int_as_float(__shfl(mp.y, k + 3));
            float2 v0 = *reinterpret_cast<const float2*>(&feat[(size_t)s0 * FD + lane * 2]);
            float2 v1 = *reinterpret_cast<const float2*>(&feat[(size_t)s1 * FD + lane * 2]);
            float2 v2 = *reinterpret_cast<const float2*>(&feat[(size_t)s2 * FD + lane * 2]);
            float2 v3 = *reinterpret_cast<const float2*>(&feat[(size_t)s3 * FD + lane * 2]);
            acc.x += v0.x * w0 + v1.x * w1 + v2.x * w2 + v3.x * w3;
            acc.y += v0.y * w0 + v1.y * w1 + v2.y * w2 + v3.y * w3;
        }
        for (; k < cnt; ++k) {
            int s = __shfl(mp.x, k);
            float w = __int_as_float(__shfl(mp.y, k));
            float2 v = *reinterpret_cast<const float2*>(&feat[(size_t)s * FD + lane * 2]);
            acc.x += v.x * w;
            acc.y += v.y * w;
        }
    }
    float inv = 1.0f / fmaxf((float)(end - start), 1.0f);
    size_t o = (size_t)n * FD + lane * 2;
    float2 r;
    if (xm) {
        const float2 x = *reinterpret_cast<const float2*>(&xm[o]);
        r.x = (acc.x * inv + x.x) * 0.5f;
        r.y = (acc.y * inv + x.y) * 0.5f;
    } else {
        r.x = acc.x * inv;
        r.y = acc.y * inv;
    }
    *reinterpret_cast<float2*>(&out[o]) = r;
}

// ---------------- unweighted gather-mean, unroll-4 ----------------
__global__ __launch_bounds__(256) void k_gather_u(const float* __restrict__ feat,
                                                  const int* __restrict__ csr_src,
                                                  const int* __restrict__ rowptr,
                                                  const float* __restrict__ xm,
                                                  float* __restrict__ out, int N) {
    int n = blockIdx.x * 4 + (threadIdx.x >> 6);
    if (n >= N) return;
    int lane = threadIdx.x & 63;
    int start = rowptr[n], end = rowptr[n + 1];
    float2 acc = make_float2(0.f, 0.f);
    for (int base = start; base < end; base += 64) {
        int cnt = min(64, end - base);
        int myi = (base + lane < end) ? csr_src[base + lane] : 0;
        int k = 0;
        for (; k + 4 <= cnt; k += 4) {
            int s0 = __shfl(myi, k),     s1 = __shfl(myi, k + 1);
            int s2 = __shfl(myi, k + 2), s3 = __shfl(myi, k + 3);
            float2 v0 = *reinterpret_cast<const float2*>(&feat[(size_t)s0 * FD + lane * 2]);
            float2 v1 = *reinterpret_cast<const float2*>(&feat[(size_t)s1 * FD + lane * 2]);
            float2 v2 = *reinterpret_cast<const float2*>(&feat[(size_t)s2 * FD + lane * 2]);
            float2 v3 = *reinterpret_cast<const float2*>(&feat[(size_t)s3 * FD + lane * 2]);
            acc.x += v0.x + v1.x + v2.x + v3.x;
            acc.y += v0.y + v1.y + v2.y + v3.y;
        }
        for (; k < cnt; ++k) {
            int s = __shfl(myi, k);
            float2 v = *reinterpret_cast<const float2*>(&feat[(size_t)s * FD + lane * 2]);
            acc.x += v.x;
            acc.y += v.y;
        }
    }
    float inv = 1.0f / fmaxf((float)(end - start), 1.0f);
    size_t o = (size_t)n * FD + lane * 2;
    float2 r;
    if (xm) {
        const float2 x = *reinterpret_cast<const float2*>(&xm[o]);
        r.x = (acc.x * inv + x.x) * 0.5f;
        r.y = (acc.y * inv + x.y) * 0.5f;
    } else {
        r.x = acc.x * inv;
        r.y = acc.y * inv;
    }
    *reinterpret_cast<float2*>(&out[o]) = r;
}

// ---------------- fused triple gather over CSR 3 (e1s), unroll-2 ----------------
// s1s <- mean(net1[e1d])            (UNWEIGHTED — short_path back-scatter)
// s121 <- mean(n3_12[e1d] * w1)     (weighted — long-path final hop)
// s131 <- mean(n3_13[e1d] * w1)     (weighted)
__global__ __launch_bounds__(256) void k_gather3_w(const float* __restrict__ f1,
                                                   const float* __restrict__ f2,
                                                   const float* __restrict__ f3,
                                                   const int2* __restrict__ pairs,
                                                   const int* __restrict__ rowptr,
                                                   float* __restrict__ o1,
                                                   float* __restrict__ o2,
                                                   float* __restrict__ o3, int N) {
    int n = blockIdx.x * 4 + (threadIdx.x >> 6);
    if (n >= N) return;
    int lane = threadIdx.x & 63;
    int start = rowptr[n], end = rowptr[n + 1];
    float2 a1 = make_float2(0.f, 0.f), a2 = a1, a3 = a1;
    for (int base = start; base < end; base += 64) {
        int cnt = min(64, end - base);
        int2 mp = (base + lane < end) ? pairs[base + lane] : make_int2(0, 0);
        int k = 0;
        for (; k + 2 <= cnt; k += 2) {
            int sA = __shfl(mp.x, k), sB = __shfl(mp.x, k + 1);
            float wA = __int_as_float(__shfl(mp.y, k));
            float wB = __int_as_float(__shfl(mp.y, k + 1));
            size_t oA = (size_t)sA * FD + lane * 2;
            size_t oB = (size_t)sB * FD + lane * 2;
            float2 v1A = *reinterpret_cast<const float2*>(&f1[oA]);
            float2 v2A = *reinterpret_cast<const float2*>(&f2[oA]);
            float2 v3A = *reinterpret_cast<const float2*>(&f3[oA]);
            float2 v1B = *reinterpret_cast<const float2*>(&f1[oB]);
            float2 v2B = *reinterpret_cast<const float2*>(&f2[oB]);
            float2 v3B = *reinterpret_cast<const float2*>(&f3[oB]);
            a1.x += v1A.x + v1B.x;            a1.y += v1A.y + v1B.y;            // unweighted
            a2.x += v2A.x * wA + v2B.x * wB;  a2.y += v2A.y * wA + v2B.y * wB;
            a3.x += v3A.x * wA + v3B.x * wB;  a3.y += v3A.y * wA + v3B.y * wB;
        }
        for (; k < cnt; ++k) {
            int s = __shfl(mp.x, k);
            float w = __int_as_float(__shfl(mp.y, k));
            size_t oo = (size_t)s * FD + lane * 2;
            float2 v1 = *reinterpret_cast<const float2*>(&f1[oo]);
            float2 v2 = *reinterpret_cast<const float2*>(&f2[oo]);
            float2 v3 = *reinterpret_cast<const float2*>(&f3[oo]);
            a1.x += v1.x;      a1.y += v1.y;                                    // unweighted
            a2.x += v2.x * w;  a2.y += v2.y * w;
            a3.x += v3.x * w;  a3.y += v3.y * w;
        }
    }
    float inv = 1.0f / fmaxf((float)(end - start), 1.0f);
    size_t o = (size_t)n * FD + lane * 2;
    *reinterpret_cast<float2*>(&o1[o]) = make_float2(a1.x * inv, a1.y * inv);
    *reinterpret_cast<float2*>(&o2[o]) = make_float2(a2.x * inv, a2.y * inv);
    *reinterpret_cast<float2*>(&o3[o]) = make_float2(a3.x * inv, a3.y * inv);
}

// ------- lin_relu v2, in-place: xio[n,:] = relu(xio[n,:] @ W^T + b) -------
__global__ __launch_bounds__(256) void k_linrelu2(float* __restrict__ xio,
                                                  const float* __restrict__ W,
                                                  const float* __restrict__ b, int N) {
    __shared__ float Wl[128 * 128];
    __shared__ float xs[32][128];
    const int t = threadIdx.x;
#pragma unroll
    for (int q = 0; q < 16; ++q) {
        int lin = (q * 256 + t) * 4;
        int o = lin >> 7;
        int i = lin & 127;
        float4 wv = *reinterpret_cast<const float4*>(&W[lin]);
        int sw = o & 15;
        int k0 = (i >> 1) ^ sw;
        int k1 = ((i >> 1) + 1) ^ sw;
        *reinterpret_cast<float2*>(&Wl[o * 128 + (k0 << 1)]) = make_float2(wv.x, wv.y);
        *reinterpret_cast<float2*>(&Wl[o * 128 + (k1 << 1)]) = make_float2(wv.z, wv.w);
    }
    const int oc = t & 31;
    const int rg = t >> 5;
    const int sw = oc & 15;
    float bias[4] = {b[oc], b[oc + 32], b[oc + 64], b[oc + 96]};

    const int ntiles = (N + 31) >> 5;
    for (int tile = blockIdx.x; tile < ntiles; tile += gridDim.x) {
        const int row0 = tile << 5;
        __syncthreads();
        {
            int r = t >> 3;
            int c = (t & 7) * 16;
            int row = row0 + r;
            float4* dst = reinterpret_cast<float4*>(&xs[r][c]);
            if (row < N) {
                const float4* src = reinterpret_cast<const float4*>(&xio[(size_t)row * FD + c]);
                dst[0] = src[0]; dst[1] = src[1]; dst[2] = src[2]; dst[3] = src[3];
            } else {
                float4 z = make_float4(0.f, 0.f, 0.f, 0.f);
                dst[0] = z; dst[1] = z; dst[2] = z; dst[3] = z;
            }
        }
        __syncthreads();
        float acc[4][4];
#pragma unroll
        for (int j = 0; j < 4; ++j)
#pragma unroll
            for (int c = 0; c < 4; ++c) acc[j][c] = bias[c];
#pragma unroll 8
        for (int c2 = 0; c2 < 64; ++c2) {
            int wcol = ((c2 ^ sw) << 1);
            float2 w0 = *reinterpret_cast<const float2*>(&Wl[(oc     ) * 128 + wcol]);
            float2 w1 = *reinterpret_cast<const float2*>(&Wl[(oc + 32) * 128 + wcol]);
            float2 w2 = *reinterpret_cast<const float2*>(&Wl[(oc + 64) * 128 + wcol]);
            float2 w3 = *reinterpret_cast<const float2*>(&Wl[(oc + 96) * 128 + wcol]);
            int xcol = c2 << 1;
            float2 x0 = *reinterpret_cast<const float2*>(&xs[rg * 4 + 0][xcol]);
            float2 x1 = *reinterpret_cast<const float2*>(&xs[rg * 4 + 1][xcol]);
            float2 x2 = *reinterpret_cast<const float2*>(&xs[rg * 4 + 2][xcol]);
            float2 x3 = *reinterpret_cast<const float2*>(&xs[rg * 4 + 3][xcol]);
            acc[0][0] += x0.x * w0.x + x0.y * w0.y;
            acc[0][1] += x0.x * w1.x + x0.y * w1.y;
            acc[0][2] += x0.x * w2.x + x0.y * w2.y;
            acc[0][3] += x0.x * w3.x + x0.y * w3.y;
            acc[1][0] += x1.x * w0.x + x1.y * w0.y;
            acc[1][1] += x1.x * w1.x + x1.y * w1.y;
            acc[1][2] += x1.x * w2.x + x1.y * w2.y;
            acc[1][3] += x1.x * w3.x + x1.y * w3.y;
            acc[2][0] += x2.x * w0.x + x2.y * w0.y;
            acc[2][1] += x2.x * w1.x + x2.y * w1.y;
            acc[2][2] += x2.x * w2.x + x2.y * w2.y;
            acc[2][3] += x2.x * w3.x + x2.y * w3.y;
            acc[3][0] += x3.x * w0.x + x3.y * w0.y;
            acc[3][1] += x3.x * w1.x + x3.y * w1.y;
            acc[3][2] += x3.x * w2.x + x3.y * w2.y;
            acc[3][3] += x3.x * w3.x + x3.y * w3.y;
        }
#pragma unroll
        for (int j = 0; j < 4; ++j) {
            int row = row0 + rg * 4 + j;
            if (row < N) {
                size_t base = (size_t)row * FD;
                xio[base + oc]      = fmaxf(acc[j][0], 0.f);
                xio[base + oc + 32] = fmaxf(acc[j][1], 0.f);
                xio[base + oc + 64] = fmaxf(acc[j][2], 0.f);
                xio[base + oc + 96] = fmaxf(acc[j][3], 0.f);
            }
        }
    }
}

// ------- attention mix -------
__global__ __launch_bounds__(128) void k_att(const float* __restrict__ s0, const float* __restrict__ s1,
                                             const float* __restrict__ s2, const float* __restrict__ s3,
                                             const float* __restrict__ s4, const float* __restrict__ attv,
                                             float* __restrict__ out, int N0) {
    int n = blockIdx.x;
    int d = threadIdx.x;
    size_t base = (size_t)n * FD + d;
    float a0 = s0[base], a1 = s1[base], a2 = s2[base], a3 = s3[base], a4 = s4[base];
    float part[5];
    part[0] = a0 * attv[0 * FD + d];
    part[1] = a1 * attv[1 * FD + d];
    part[2] = a2 * attv[2 * FD + d];
    part[3] = a3 * attv[3 * FD + d];
    part[4] = a4 * attv[4 * FD + d];
    __shared__ float red[5][2];
    int lane = d & 63, wv = d >> 6;
#pragma unroll
    for (int p = 0; p < 5; ++p) {
        float v = part[p];
#pragma unroll
        for (int off = 32; off >= 1; off >>= 1) v += __shfl_down(v, off);
        if (lane == 0) red[p][wv] = v;
    }
    __syncthreads();
    float sc[5], m = -1e30f, ssum = 0.f;
#pragma unroll
    for (int p = 0; p < 5; ++p) { sc[p] = red[p][0] + red[p][1]; m = fmaxf(m, sc[p]); }
#pragma unroll
    for (int p = 0; p < 5; ++p) { sc[p] = __expf(sc[p] - m); ssum += sc[p]; }
    float inv = 1.0f / ssum;
    out[base] = (a0 * sc[0] + a1 * sc[1] + a2 * sc[2] + a3 * sc[3] + a4 * sc[4]) * inv;
}

extern "C" void kernel_launch(void* const* d_in, const int* in_sizes, int n_in,
                              void* d_out, int out_size, void* d_ws, size_t ws_size,
                              hipStream_t stream) {
    const float* x_node = (const float*)d_in[0];
    const float* x1 = (const float*)d_in[1];
    const float* x2 = (const float*)d_in[2];
    const float* x3 = (const float*)d_in[3];
    const float* w1 = (const float*)d_in[4];
    const float* w2 = (const float*)d_in[5];
    const float* w3 = (const float*)d_in[6];
    const float* W1 = (const float*)d_in[7];
    const float* b1 = (const float*)d_in[8];
    const float* W2 = (const float*)d_in[9];
    const float* b2 = (const float*)d_in[10];
    const float* W3 = (const float*)d_in[11];
    const float* b3 = (const float*)d_in[12];
    const float* W121 = (const float*)d_in[13];
    const float* b121 = (const float*)d_in[14];
    const float* W131 = (const float*)d_in[15];
    const float* b131 = (const float*)d_in[16];
    const float* attv = (const float*)d_in[17];
    const int* e1s = (const int*)d_in[18];
    const int* e1d = (const int*)d_in[19];
    const int* e2s = (const int*)d_in[20];
    const int* e2d = (const int*)d_in[21];
    const int* e3s = (const int*)d_in[22];
    const int* e3d = (const int*)d_in[23];
    const int* e12s = (const int*)d_in[24];
    const int* e12d = (const int*)d_in[25];
    const int* e13s = (const int*)d_in[26];
    const int* e13d = (const int*)d_in[27];

    const int N0 = in_sizes[0] / FD;
    const int N1 = in_sizes[1] / FD;
    const int N2 = in_sizes[2] / FD;
    const int N3 = in_sizes[3] / FD;
    const int E = in_sizes[4];
    const int E12 = in_sizes[24];

    // ---------------- workspace layout ----------------
    char* wsb = (char*)d_ws;
    size_t off = 0;
    auto alloc_f = [&](size_t n) { float* p = (float*)(wsb + off); off += n * 4; return p; };
    auto alloc_i = [&](size_t n) { int* p = (int*)(wsb + off); off += n * 4; return p; };

    float* s1s  = alloc_f((size_t)N0 * FD);
    float* s2s  = alloc_f((size_t)N0 * FD);
    float* s3s  = alloc_f((size_t)N0 * FD);
    float* s121 = alloc_f((size_t)N0 * FD);
    float* s131 = alloc_f((size_t)N0 * FD);
    float* net1 = alloc_f((size_t)N1 * FD);
    float* A2   = alloc_f((size_t)N2 * FD);   // net2, later m2_12
    float* A3   = alloc_f((size_t)N3 * FD);   // net3, later m2_13
    float* B12  = alloc_f((size_t)N1 * FD);   // n3 of path s-1-2-1-s
    float* B13  = alloc_f((size_t)N1 * FD);   // n3 of path s-1-3-1-s
    size_t featureBytes = off;                // staging aliases this region (dead until gathers)

    // CSR table: 0:e1d(N1,E,w1,P) 1:e2d(N2,E,w2,P) 2:e3d(N3,E,w3,P) 3:e1s(N0,E,w1,P)
    //            4:e2s(N0,E) 5:e3s(N0,E) 6:e12d(N2,E12) 7:e12s(N1,E12)
    //            8:e13d(N3,E12) 9:e13s(N1,E12)
    const int   csrN[NCSR]    = {N1, N2, N3, N0, N0, N0, N2, N1, N3, N1};
    const int   csrE[NCSR]    = {E, E, E, E, E, E, E12, E12, E12, E12};
    const int*  csrKey[NCSR]  = {e1d, e2d, e3d, e1s, e2s, e3s, e12d, e12s, e13d, e13s};
    const int*  csrVal[NCSR]  = {e1s, e2s, e3s, e1d, e2d, e3d, e12s, e12d, e13s, e13d};
    const float* csrWin[NCSR] = {w1, w2, w3, w1, nullptr, nullptr, nullptr, nullptr, nullptr, nullptr};

    size_t degStart = off;
    int* deg[NCSR]; int* rowptr[NCSR]; int* cursor[NCSR]; int* bcur[NCSR]; int* dst[NCSR];
    for (int c = 0; c < NCSR; ++c) deg[c] = alloc_i(csrN[c]);
    size_t degBytes = off - degStart;
    for (int c = 0; c < NCSR; ++c) rowptr[c] = alloc_i(csrN[c] + 1);
    for (int c = 0; c < NCSR; ++c) cursor[c] = alloc_i(csrN[c]);
    for (int c = 0; c < NCSR; ++c) bcur[c] = alloc_i(((csrN[c] + 255) >> 8));
    for (int c = 0; c < NCSR; ++c) dst[c] = alloc_i(csrWin[c] ? (size_t)csrE[c] * 2 : (size_t)csrE[c]);

    // staging records (int4) alias the feature-buffer region at offset 0
    int4* stage[NCSR];
    {
        size_t soff = 0;
        for (int c = 0; c < NCSR; ++c) { stage[c] = (int4*)(wsb + soff); soff += (size_t)csrE[c] * 16; }
        // soff = 102.4 MB <= featureBytes (192 MB); staging is dead before any feature write
        (void)featureBytes;
    }

    const int TB = 256;
    auto cdiv = [](long long a, long long b) { return (int)((a + b - 1) / b); };

    // ---------------- build CSRs ----------------
    hipMemsetAsync((void*)deg[0], 0, degBytes, stream);

    HistArgs ha;
    int boff = 0;
    for (int c = 0; c < NCSR; ++c) {
        ha.key[c] = csrKey[c]; ha.deg[c] = deg[c]; ha.E[c] = csrE[c];
        ha.blkOff[c] = boff;
        boff += cdiv(csrE[c], TB);
    }
    ha.blkOff[NCSR] = boff;
    k_hist_all<<<boff, TB, 0, stream>>>(ha);

    ScanArgs sa;
    for (int c = 0; c < NCSR; ++c) {
        sa.deg[c] = deg[c]; sa.rowptr[c] = rowptr[c]; sa.cursor[c] = cursor[c];
        sa.bcur[c] = bcur[c]; sa.N[c] = csrN[c];
    }
    k_scan<<<NCSR, 1024, 0, stream>>>(sa);

    BinAArgs baa;
    int aoff = 0;
    for (int c = 0; c < NCSR; ++c) {
        baa.key[c] = csrKey[c]; baa.val[c] = csrVal[c]; baa.w[c] = csrWin[c];
        baa.bcur[c] = bcur[c]; baa.stage[c] = stage[c]; baa.E[c] = csrE[c];
        baa.paired[c] = csrWin[c] ? 1 : 0;
        baa.blkOff[c] = aoff;
        aoff += cdiv(csrE[c], TILE_A);
    }
    baa.blkOff[NCSR] = aoff;
    k_binA<<<aoff, TB, 0, stream>>>(baa);

    BinBArgs bab;
    int bboff = 0;
    for (int c = 0; c < NCSR; ++c) {
        bab.stage[c] = stage[c]; bab.rowptr[c] = rowptr[c]; bab.cursor[c] = cursor[c];
        bab.dst[c] = dst[c]; bab.N[c] = csrN[c];
        bab.paired[c] = csrWin[c] ? 1 : 0;
        bab.blkOff[c] = bboff;
        bboff += (csrN[c] + 255) >> 8;
    }
    bab.blkOff[NCSR] = bboff;
    k_binB<<<bboff, TB, 0, stream>>>(bab);

    auto gw = [&](const float* feat, int c, const float* xm, float* out, int N) {
        k_gather_w<<<cdiv(N, 4), 256, 0, stream>>>(feat, (const int2*)dst[c], rowptr[c], xm, out, N);
    };
    auto gu = [&](const float* feat, int c, const float* xm, float* out, int N) {
        k_gather_u<<<cdiv(N, 4), 256, 0, stream>>>(feat, dst[c], rowptr[c], xm, out, N);
    };
    auto linrelu = [&](float* xio, const float* W, const float* b) {
        int ntiles = (N0 + 31) >> 5;
        int grid = ntiles < 512 ? ntiles : 512;
        k_linrelu2<<<grid, 256, 0, stream>>>(xio, W, b, N0);
    };

    // ---------------- first hop (3 weighted gathers from x_node) ----------------
    gw(x_node, 0, x1, net1, N1);      // net1
    gw(x_node, 1, x2, A2, N2);        // net2
    gw(x_node, 2, x3, A3, N3);        // net3

    // ---------------- short paths 2,3 back-gather ----------------
    gu(A2, 4, nullptr, s2s, N0);
    gu(A3, 5, nullptr, s3s, N0);

    // ---------------- long path intermediates ----------------
    gu(net1, 6, x2, A2, N2);          // m2_12 -> n2_12  (A2 reuse, prior reader done)
    gu(A2, 7, x1, B12, N1);           // n3_12
    gu(net1, 8, x3, A3, N3);          // m2_13 -> n2_13
    gu(A3, 9, x1, B13, N1);           // n3_13

    // ---------------- fused triple back-gather over CSR 3 (e1s; s1s unweighted, s121/s131 * w1) ----------------
    k_gather3_w<<<cdiv(N0, 4), 256, 0, stream>>>(net1, B12, B13, (const int2*)dst[3],
                                                 rowptr[3], s1s, s121, s131, N0);

    // ---------------- lin_relu x5 ----------------
    linrelu(s1s, W1, b1);
    linrelu(s2s, W2, b2);
    linrelu(s3s, W3, b3);
    linrelu(s121, W121, b121);
    linrelu(s131, W131, b131);

    // ---------------- attention mix ----------------
    k_att<<<N0, FD, 0, stream>>>(s1s, s2s, s3s, s121, s131, attv, (float*)d_out, N0);
}